// Round 4
// baseline (2501.732 us; speedup 1.0000x reference)
//
#include <hip/hip_runtime.h>
#include <hip/hip_bf16.h>
#include <math.h>

// ============================================================================
// ResponseFilter — round 6: counted-vmcnt GEMM pipeline (T4).
//
// Round-5 counters: gemm_mfma still ~80% of runtime, MfmaUtil 24.4,
// VALUBusy 43, occ 28.6 -> __syncthreads() drains vmcnt(0) every K-step,
// so each staged tile's full HBM/L2 latency sits on the critical path
// (the documented m97-structure ceiling). This round: raw s_barrier +
// counted s_waitcnt vmcnt(4) (single asm, memory clobber), 3 LDS buffers
// (48 KB), 2 stages in flight; stage(i+2) issued right after barrier(i).
// Write-after-read safety: stage(i+2) targets buf[(i-1)%3], whose readers
// all precede barrier(i) in program order. One barrier per K-step; the
// prefetch gets ~2 compute-phases of latency cover.
// Epilogue (per-wave LDS bounce + coalesced short8 stores) unchanged.
// Attention (KV-resident), LN (wave-per-row), everything else unchanged.
// ============================================================================

#define B_  16
#define T_  32
#define L_  64
#define D_  768
#define H_  12
#define F_  2048
#define ZR_ 100
#define ZP_ 128
#define NP_ 512
#define EPS_ 1e-5f

// meta int offsets (d_ws as int*)
#define MI_NTOT  0
#define MI_NRESP 8
#define MI_OFF   32
#define MI_BIDX  64
#define MI_TIDX  576
#define MI_NODE  1088

// ws float offsets
#define WS_BIAS2 2048
#define WS_EMEAN 34816
#define WS_S     428032
#define WS_WST   428544    // bf16 weight stage, 1,769,472 ushorts (3.54 MB)
#define WS_BIG   1313280   // bf16 QKV/hidden region; fp32 Z overlay

// d_out float offsets (flat tuple: oh[512], ext_mask[32768], n_ext_adv[1],
// new_tree_lens[16], new_emb[25165824], new_msk[32768])
#define OUT_OH   0
#define OUT_EXT  512
#define OUT_NEA  33280
#define OUT_NTL  33281
#define OUT_NEMB 33297
#define OUT_NMSK 25199121
#define OUT_XSCR 33300   // bf16 X scratch (16B aligned), 32768*768 ushorts

typedef __attribute__((ext_vector_type(8))) short short8;
typedef __attribute__((ext_vector_type(4))) float f32x4;

__device__ inline float bf2f(unsigned s) {
  return __uint_as_float((s & 0xffffu) << 16);
}
__device__ inline unsigned short f2bf(float x) {
  unsigned u = __float_as_uint(x);
  u += 0x7fffu + ((u >> 16) & 1u);      // round-to-nearest-even
  return (unsigned short)(u >> 16);
}
__device__ inline unsigned pack2(float a, float b) {
  return (unsigned)f2bf(a) | ((unsigned)f2bf(b) << 16);
}

// ---------------------------------------------------------------------------
__global__ void meta_kernel(const int* __restrict__ tl, int* __restrict__ mi) {
  if (threadIdx.x != 0) return;
  int off = 0;
  for (int b = 0; b < B_; b++) {
    int nr = tl[b] - 1;
    mi[MI_NRESP + b] = nr;
    mi[MI_OFF + b] = off;
    off += nr;
  }
  mi[MI_NTOT] = off;
  for (int j = 0; j < NP_; j++) {
    int b = -1, t = 0;
    if (j < off) {
      b = 0;
      while (b + 1 < B_ && j >= mi[MI_OFF + b + 1]) b++;
      t = j - mi[MI_OFF + b] + 1;
    }
    mi[MI_BIDX + j] = b;
    mi[MI_TIDX + j] = t;
  }
}

// ---------------------------------------------------------------------------
// fp32 -> bf16 weight conversion (n multiple of 1024)
__global__ __launch_bounds__(256) void w2bf_kernel(const float* __restrict__ W,
                                                   unsigned short* __restrict__ o) {
  const int i = (blockIdx.x * 256 + threadIdx.x) * 4;
  float4 v = *(const float4*)(W + i);
  uint2 pk; pk.x = pack2(v.x, v.y); pk.y = pack2(v.z, v.w);
  *(uint2*)(o + i) = pk;
}

// ---------------------------------------------------------------------------
// X[j,l,:] bf16 = reply embedding (zero for padded j); bias2 = mask or -1e30
__global__ __launch_bounds__(192) void gather_kernel(
    const float* __restrict__ emb, const float* __restrict__ am,
    const int* __restrict__ mi, unsigned short* __restrict__ X,
    float* __restrict__ bias2) {
  const int blk = blockIdx.x;          // j*64 + l
  const int j = blk >> 6, l = blk & 63;
  const int ntot = mi[MI_NTOT];
  const int t = threadIdx.x;
  float4 v = make_float4(0.f, 0.f, 0.f, 0.f);
  if (j < ntot) {
    const int b = mi[MI_BIDX + j], tt = mi[MI_TIDX + j];
    v = ((const float4*)(emb + (size_t)((b * T_ + tt) * L_ + l) * D_))[t];
    if (t == 0) bias2[blk] = am[(b * T_ + tt) * L_ + l];
  } else {
    if (t == 0) bias2[blk] = -1e30f;
  }
  uint2 pk; pk.x = pack2(v.x, v.y); pk.y = pack2(v.z, v.w);
  *(uint2*)(X + (size_t)blk * D_ + t * 4) = pk;
}

// ---------------------------------------------------------------------------
__global__ __launch_bounds__(256) void emean_kernel(const unsigned short* __restrict__ X,
                                                    float* __restrict__ em) {
  const int j = blockIdx.x;
  int d = threadIdx.x;
  for (int c = 0; c < 3; c++, d += 256) {
    const unsigned short* p = X + (size_t)j * L_ * D_ + d;
    float s = 0.f;
    for (int l = 0; l < L_; l++) s += bf2f(p[l * D_]);
    em[j * D_ + d] = s * (1.f / 64.f);
  }
}

// ---------------------------------------------------------------------------
__device__ inline float blockSum256(float v, float* red) {
  #pragma unroll
  for (int o = 32; o > 0; o >>= 1) v += __shfl_down(v, o);
  const int lane = threadIdx.x & 63, wid = threadIdx.x >> 6;
  __syncthreads();
  if (lane == 0) red[wid] = v;
  __syncthreads();
  return red[0] + red[1] + red[2] + red[3];
}

// in-place LN, wave-per-row (4 rows/block, no barriers); skips padded rows
__global__ __launch_bounds__(256) void ln_kernel(unsigned short* __restrict__ X,
                                                 const float* __restrict__ g,
                                                 const float* __restrict__ bb,
                                                 const int* __restrict__ mi) {
  const int row = blockIdx.x * 4 + (threadIdx.x >> 6);
  if (row >= mi[MI_NTOT] * L_) return;
  const int lane = threadIdx.x & 63;
  unsigned short* p = X + (size_t)row * D_;
  float v[12];
  #pragma unroll
  for (int c = 0; c < 3; c++) {
    uint2 u = *(const uint2*)(p + lane * 4 + c * 256);
    v[c * 4 + 0] = bf2f(u.x); v[c * 4 + 1] = bf2f(u.x >> 16);
    v[c * 4 + 2] = bf2f(u.y); v[c * 4 + 3] = bf2f(u.y >> 16);
  }
  float s = 0.f;
  #pragma unroll
  for (int i = 0; i < 12; i++) s += v[i];
  #pragma unroll
  for (int o = 32; o > 0; o >>= 1) s += __shfl_xor(s, o);
  const float m = s * (1.f / 768.f);
  float q = 0.f;
  #pragma unroll
  for (int i = 0; i < 12; i++) { v[i] -= m; q += v[i] * v[i]; }
  #pragma unroll
  for (int o = 32; o > 0; o >>= 1) q += __shfl_xor(q, o);
  const float r = rsqrtf(q * (1.f / 768.f) + EPS_);
  #pragma unroll
  for (int c = 0; c < 3; c++) {
    const int d = lane * 4 + c * 256;
    float4 gv = *(const float4*)(g + d);
    float4 bv = *(const float4*)(bb + d);
    uint2 pk;
    pk.x = pack2(v[c * 4 + 0] * r * gv.x + bv.x, v[c * 4 + 1] * r * gv.y + bv.y);
    pk.y = pack2(v[c * 4 + 2] * r * gv.z + bv.z, v[c * 4 + 3] * r * gv.w + bv.w);
    *(uint2*)(p + d) = pk;
  }
}

// ---------------------------------------------------------------------------
// MFMA bf16 GEMM: C[M,N] = [C +] act(A @ W^T + bias). 128x128 tile, 256 thr
// (4 waves 2x2, each 64x64 via 4x4 of 16x16x32 MFMA). K mult of 32, N mult
// of 128. Counted-vmcnt pipeline: 3 LDS buffers, 2 stages in flight;
// per K-step: {s_waitcnt vmcnt(4); s_barrier} (one asm, no compiler drain)
// -> STAGE(i+2) -> COMPUTE(i). stage(i+2) targets buf[(i-1)%3], whose
// readers all precede barrier(i) -> race-free with ONE barrier per step.
// LDS k-group XOR swizzle: slot (row, sp) holds kg = sp ^ ((row>>1)&3).
// Epilogue: acc -> per-wave 8KB LDS slice -> coalesced short8 stores
// (+ residual add at readback for ADD).
template <int ACT, bool ADD>
__global__ __launch_bounds__(256) void gemm_mfma(
    const unsigned short* __restrict__ A, int lda, int K,
    const unsigned short* __restrict__ W, int ldw,
    const float* __restrict__ bias,
    unsigned short* __restrict__ C, int ldc,
    const int* __restrict__ mi) {
  const int rows = mi[MI_NTOT] * 64;
  const int row0 = blockIdx.x * 128;
  if (row0 >= rows) return;
  const int col0 = blockIdx.y * 128;
  __shared__ unsigned short Sh[6 * 4096];   // 3 A bufs + 3 B bufs (48 KB)
  unsigned short* SA = Sh;
  unsigned short* SB = Sh + 3 * 4096;
  const int t = threadIdx.x;
  const int lane = t & 63, w = t >> 6;
  const int wr = w >> 1, wc = w & 1;
  const int quad = lane >> 4, l15 = lane & 15;
  f32x4 acc[4][4];
  #pragma unroll
  for (int i = 0; i < 4; i++)
    #pragma unroll
    for (int j = 0; j < 4; j++) acc[i][j] = (f32x4){0.f, 0.f, 0.f, 0.f};

  // per-lane staging coords (2 chunks per wave per tile, per matrix)
  int schunk[2];
  const unsigned short* gA[2];
  const unsigned short* gB[2];
  #pragma unroll
  for (int r = 0; r < 2; r++) {
    const int c = r * 4 + w;
    const int g = c * 64 + lane;
    const int row = g >> 2, slot = g & 3;
    const int kg = slot ^ ((row >> 1) & 3);
    schunk[r] = c;
    gA[r] = A + (size_t)(row0 + row) * lda + kg * 8;
    gB[r] = W + (size_t)(col0 + row) * ldw + kg * 8;
  }
  // fragment LDS offsets (ushorts)
  int aoff[4], boff[4];
  #pragma unroll
  for (int m = 0; m < 4; m++) {
    const int ar = wr * 64 + m * 16 + l15;
    aoff[m] = ar * 32 + (quad ^ ((ar >> 1) & 3)) * 8;
    const int bn = wc * 64 + m * 16 + l15;
    boff[m] = bn * 32 + (quad ^ ((bn >> 1) & 3)) * 8;
  }

#define STAGE_(bi_, kk_)                                                       \
  { const int _off = (bi_) * 4096;                                             \
    _Pragma("unroll")                                                          \
    for (int r = 0; r < 2; r++) {                                              \
      __builtin_amdgcn_global_load_lds(                                        \
          (const __attribute__((address_space(1))) void*)(gA[r] + (kk_)),      \
          (__attribute__((address_space(3))) void*)(SA + _off + schunk[r] * 512), \
          16, 0, 0);                                                           \
      __builtin_amdgcn_global_load_lds(                                        \
          (const __attribute__((address_space(1))) void*)(gB[r] + (kk_)),      \
          (__attribute__((address_space(3))) void*)(SB + _off + schunk[r] * 512), \
          16, 0, 0);                                                           \
    } }

#define COMPUTE_(bi_)                                                          \
  {                                                                            \
    const int _off = (bi_) * 4096;                                             \
    short8 af[4], bfr[4];                                                      \
    _Pragma("unroll")                                                          \
    for (int m = 0; m < 4; m++) {                                              \
      af[m]  = *(const short8*)(SA + _off + aoff[m]);                          \
      bfr[m] = *(const short8*)(SB + _off + boff[m]);                          \
    }                                                                          \
    _Pragma("unroll")                                                          \
    for (int m = 0; m < 4; m++)                                                \
      _Pragma("unroll")                                                        \
      for (int n = 0; n < 4; n++)                                              \
        acc[m][n] = __builtin_amdgcn_mfma_f32_16x16x32_bf16(af[m], bfr[n],     \
                                                            acc[m][n], 0, 0, 0); \
  }

  const int NS = K >> 5;     // K-steps of 32 (all call sites have NS >= 2)
  STAGE_(0, 0);
  STAGE_(1, 32);
  int bi = 0;
  for (int i = 0; i < NS; i++) {
    if (i + 1 < NS) {
      asm volatile("s_waitcnt vmcnt(4)\ns_barrier" ::: "memory");
    } else {
      asm volatile("s_waitcnt vmcnt(0)\ns_barrier" ::: "memory");
    }
    __builtin_amdgcn_sched_barrier(0);
    if (i + 2 < NS) {
      const int b2 = (bi >= 1) ? bi - 1 : 2;   // (i+2)%3
      STAGE_(b2, (i + 2) * 32);
    }
    COMPUTE_(bi);
    bi = (bi >= 2) ? 0 : bi + 1;
  }
  __syncthreads();           // LDS now dead -> reuse as epilogue bounce

#undef STAGE_
#undef COMPUTE_

  // epilogue: C/D layout col = lane&15, row = quad*4 + reg.
  // Stage wave's 64x64 output in its private 8KB slice, then coalesced
  // short8 stores (8 per lane). Residual add (ADD) at readback.
  unsigned short* slice = Sh + w * 4096;
  float bv[4];
  #pragma unroll
  for (int n = 0; n < 4; n++) bv[n] = bias[col0 + wc * 64 + n * 16 + l15];
  #pragma unroll
  for (int m = 0; m < 4; m++) {
    #pragma unroll
    for (int reg = 0; reg < 4; reg++) {
      const int r64 = m * 16 + quad * 4 + reg;
      #pragma unroll
      for (int n = 0; n < 4; n++) {
        float x = acc[m][n][reg] + bv[n];
        if (ACT == 1) x = fmaxf(x, 0.f);
        slice[r64 * 64 + n * 16 + l15] = f2bf(x);
      }
    }
  }
  unsigned short* crow = C + (size_t)(row0 + wr * 64) * ldc + col0 + wc * 64;
  #pragma unroll
  for (int i = 0; i < 8; i++) {
    const int j = i * 64 + lane;             // 16B chunk 0..511 of 64x64 tile
    const int r64 = j >> 3, c8 = (j & 7) * 8;
    short8 v = *(const short8*)(slice + j * 8);
    unsigned short* cp = crow + (size_t)r64 * ldc + c8;
    if (ADD) {
      short8 cv = *(const short8*)cp;
      #pragma unroll
      for (int e = 0; e < 8; e++)
        v[e] = (short)f2bf(bf2f((unsigned short)v[e]) +
                           bf2f((unsigned short)cv[e]));
    }
    *(short8*)cp = v;
  }
}

// ---------------------------------------------------------------------------
// VALU GEMM (kept for ragged pe/pd only): C = act(A @ W^T + b)
// AT: 0 fp32 A, 1 bf16 A.  CT: 0 fp32 C, 1 bf16 C.
template <int ACT, int AT, int CT>
__global__ __launch_bounds__(256) void gemm_kernel(
    const void* __restrict__ Av, int lda, int kloop,
    const float* __restrict__ W, int kw, int nreal,
    const float* __restrict__ bias,
    void* __restrict__ Cv, int ldc,
    const int* __restrict__ mi) {
  if ((int)blockIdx.x >= mi[MI_NTOT]) return;
  __shared__ float As[16][68];
  __shared__ float Ws[16][68];
  const int t = threadIdx.x;
  const int tx = t & 15, ty = t >> 4;
  const int lrow = t >> 2, lkg = (t & 3) * 4;
  const size_t row0 = (size_t)blockIdx.x * 64;
  const int col0 = blockIdx.y * 64;
  float acc[4][4] = {};
  for (int k0 = 0; k0 < kloop; k0 += 16) {
    float a4[4];
    if (AT == 0) {
      float4 av = *(const float4*)((const float*)Av + (row0 + lrow) * (size_t)lda + k0 + lkg);
      a4[0] = av.x; a4[1] = av.y; a4[2] = av.z; a4[3] = av.w;
    } else {
      uint2 u = *(const uint2*)((const unsigned short*)Av + (row0 + lrow) * (size_t)lda + k0 + lkg);
      a4[0] = bf2f(u.x); a4[1] = bf2f(u.x >> 16);
      a4[2] = bf2f(u.y); a4[3] = bf2f(u.y >> 16);
    }
    float wv[4];
    const int wn = col0 + lrow;
    #pragma unroll
    for (int i = 0; i < 4; i++) {
      const int k = k0 + lkg + i;
      wv[i] = (wn < nreal && k < kw) ? W[(size_t)wn * kw + k] : 0.f;
    }
    __syncthreads();
    As[lkg + 0][lrow] = a4[0]; As[lkg + 1][lrow] = a4[1];
    As[lkg + 2][lrow] = a4[2]; As[lkg + 3][lrow] = a4[3];
    Ws[lkg + 0][lrow] = wv[0]; Ws[lkg + 1][lrow] = wv[1];
    Ws[lkg + 2][lrow] = wv[2]; Ws[lkg + 3][lrow] = wv[3];
    __syncthreads();
    #pragma unroll
    for (int kk = 0; kk < 16; kk++) {
      float4 av4 = *(const float4*)(&As[kk][ty * 4]);
      float4 wv4 = *(const float4*)(&Ws[kk][tx * 4]);
      float aa[4] = {av4.x, av4.y, av4.z, av4.w};
      float ww[4] = {wv4.x, wv4.y, wv4.z, wv4.w};
      #pragma unroll
      for (int i = 0; i < 4; i++)
        #pragma unroll
        for (int j = 0; j < 4; j++) acc[i][j] += aa[i] * ww[j];
    }
  }
  const int n0 = col0 + tx * 4;
  float bv[4];
  #pragma unroll
  for (int j = 0; j < 4; j++) bv[j] = (n0 + j < nreal) ? bias[n0 + j] : 0.f;
  #pragma unroll
  for (int i = 0; i < 4; i++) {
    float v[4];
    #pragma unroll
    for (int j = 0; j < 4; j++) {
      float x = acc[i][j] + bv[j];
      if (ACT == 1) x = fmaxf(x, 0.f);
      if (ACT == 2) x = tanhf(x);
      v[j] = x;
    }
    if (CT == 0) {
      float* cp = (float*)Cv + (row0 + ty * 4 + i) * (size_t)ldc + n0;
      *(float4*)cp = make_float4(v[0], v[1], v[2], v[3]);
    } else {
      unsigned short* cp = (unsigned short*)Cv + (row0 + ty * 4 + i) * (size_t)ldc + n0;
      uint2 pk; pk.x = pack2(v[0], v[1]); pk.y = pack2(v[2], v[3]);
      *(uint2*)cp = pk;
    }
  }
}

// ---------------------------------------------------------------------------
// MFMA attention, KV-resident: one block per (l, h), 8 waves (512 thr).
// Stage ALL K (global_load_lds, pre-swizzled source -> linear LDS) and V^T
// (manual transpose scatter) once; single barrier; then each wave free-runs
// q-tiles (16 rows/wave, 128/block) x kv-tiles with zero global loads and
// zero barriers (P staging per-wave). O bf16 overwrites Q columns of QKV
// (disjoint from staged K/V columns; each wave owns its rows -> race-free).
// LDS tile swizzle: elem(row,col) at row*64 + ((col>>3)^(row&7))*8 + (col&7).
__global__ __launch_bounds__(512) void attn_kernel(
    unsigned short* __restrict__ QKV, const float* __restrict__ bias2,
    const int* __restrict__ mi) {
  const int ntot = mi[MI_NTOT];
  const int l = blockIdx.x, h = blockIdx.y;
  const int ntk = (ntot + 63) >> 6;     // kv tiles (padded keys masked by bias)
  __shared__ unsigned short Ks[512 * 64];   // K rows [m][d], swizzled
  __shared__ unsigned short Vt[8 * 4096];   // per-tile V^T [d][m], swizzled
  __shared__ unsigned short Ps[8][1024];    // per-wave P / O-bounce
  __shared__ float bs[512];                 // bias column for this l
  const int t = threadIdx.x;
  const int lane = t & 63, w = t >> 6;
  const int quad = lane >> 4, l15 = lane & 15;

  // ---- stage K: linear LDS dst, source chunk pre-swizzled so slot g of row
  // m holds chunk g ^ (m&7) (matches the ds_read swizzle below)
  {
    const int sub = lane >> 3;              // low 3 bits of m
    const int cc = (lane & 7) ^ sub;        // source chunk for this slot
    for (int it = 0; it < ntk; it++) {
      const int m = it * 64 + w * 8 + sub;
      const unsigned short* src =
          QKV + (size_t)(m * L_ + l) * 2304 + 768 + h * 64 + cc * 8;
      __builtin_amdgcn_global_load_lds(
          (const __attribute__((address_space(1))) void*)src,
          (__attribute__((address_space(3))) void*)(Ks + it * 4096 + w * 512),
          16, 0, 0);
    }
  }
  // ---- stage V transposed: thread t -> m = t&63, d in [(t>>6)*8, +8)
  {
    const int m = t & 63;
    const int d0 = (t >> 6) * 8;
    for (int mt = 0; mt < ntk; mt++) {
      short8 v = *(const short8*)(
          QKV + (size_t)((mt * 64 + m) * L_ + l) * 2304 + 1536 + h * 64 + d0);
      #pragma unroll
      for (int i = 0; i < 8; i++) {
        const int d = d0 + i;
        Vt[mt * 4096 + d * 64 + (((m >> 3) ^ (d & 7)) * 8) + (m & 7)] =
            (unsigned short)v[i];
      }
    }
  }
  // ---- stage bias column (padded m already -1e30 from gather)
  bs[t] = bias2[t * 64 + l];
  __syncthreads();

  const int nqt = (ntot + 127) >> 7;
  for (int qt = 0; qt < nqt; qt++) {
    const int qbase = qt * 128 + w * 16;
    if (qbase >= ntot) continue;

    // Q A-frags direct from global (2 x 16B per lane)
    short8 af[2];
    #pragma unroll
    for (int kc = 0; kc < 2; kc++)
      af[kc] = *(const short8*)(
          QKV + (size_t)((qbase + l15) * L_ + l) * 2304 + h * 64 + (kc * 4 + quad) * 8);

    f32x4 oa[4];
    float runmax[4], runsum[4];
    #pragma unroll
    for (int f = 0; f < 4; f++) oa[f] = (f32x4){0.f, 0.f, 0.f, 0.f};
    #pragma unroll
    for (int r2 = 0; r2 < 4; r2++) { runmax[r2] = -3.0e38f; runsum[r2] = 0.f; }

    for (int mt = 0; mt < ntk; mt++) {
      // ---- S = Q @ K^T  (C layout: row q = quad*4+reg, col m = cb*16+l15)
      f32x4 sv[4];
      #pragma unroll
      for (int cb = 0; cb < 4; cb++) {
        sv[cb] = (f32x4){0.f, 0.f, 0.f, 0.f};
        const int mrow = mt * 64 + cb * 16 + l15;
        #pragma unroll
        for (int kc = 0; kc < 2; kc++) {
          short8 bk = *(const short8*)(
              Ks + mrow * 64 + (((kc * 4 + quad) ^ (mrow & 7)) * 8));
          sv[cb] = __builtin_amdgcn_mfma_f32_16x16x32_bf16(af[kc], bk, sv[cb], 0, 0, 0);
        }
      }

      // ---- online softmax (state per q-row = quad*4+reg)
      float bj[4];
      #pragma unroll
      for (int cb = 0; cb < 4; cb++) bj[cb] = bs[mt * 64 + cb * 16 + l15];
      float pj[4][4];   // [cb][reg]
      #pragma unroll
      for (int cb = 0; cb < 4; cb++)
        #pragma unroll
        for (int r2 = 0; r2 < 4; r2++) pj[cb][r2] = sv[cb][r2] * 0.125f + bj[cb];
      float tmax[4];
      #pragma unroll
      for (int r2 = 0; r2 < 4; r2++)
        tmax[r2] = fmaxf(fmaxf(pj[0][r2], pj[1][r2]), fmaxf(pj[2][r2], pj[3][r2]));
      #pragma unroll
      for (int o2 = 1; o2 < 16; o2 <<= 1)
        #pragma unroll
        for (int r2 = 0; r2 < 4; r2++) tmax[r2] = fmaxf(tmax[r2], __shfl_xor(tmax[r2], o2));
      float tsum[4];
      #pragma unroll
      for (int r2 = 0; r2 < 4; r2++) {
        const float nmax = fmaxf(runmax[r2], tmax[r2]);
        const float alpha = __expf(runmax[r2] - nmax);
        runmax[r2] = nmax;
        float s0 = 0.f;
        #pragma unroll
        for (int cb = 0; cb < 4; cb++) { pj[cb][r2] = __expf(pj[cb][r2] - nmax); s0 += pj[cb][r2]; }
        tsum[r2] = s0;
        runsum[r2] *= alpha;
        #pragma unroll
        for (int f = 0; f < 4; f++) oa[f][r2] *= alpha;
      }
      #pragma unroll
      for (int o2 = 1; o2 < 16; o2 <<= 1)
        #pragma unroll
        for (int r2 = 0; r2 < 4; r2++) tsum[r2] += __shfl_xor(tsum[r2], o2);
      #pragma unroll
      for (int r2 = 0; r2 < 4; r2++) runsum[r2] += tsum[r2];

      // ---- P -> per-wave LDS (A-operand layout, bf16)
      #pragma unroll
      for (int cb = 0; cb < 4; cb++) {
        const int m = cb * 16 + l15;
        #pragma unroll
        for (int r2 = 0; r2 < 4; r2++) {
          const int q = quad * 4 + r2;
          Ps[w][q * 64 + (((m >> 3) ^ (q & 7)) * 8) + (m & 7)] = f2bf(pj[cb][r2]);
        }
      }
      // ---- O += P @ V
      short8 pa[2];
      #pragma unroll
      for (int kc = 0; kc < 2; kc++)
        pa[kc] = *(const short8*)(
            &Ps[w][l15 * 64 + (((kc * 4 + quad) ^ (l15 & 7)) * 8)]);
      #pragma unroll
      for (int f = 0; f < 4; f++) {
        const int d = f * 16 + l15;
        #pragma unroll
        for (int kc = 0; kc < 2; kc++) {
          short8 bv = *(const short8*)(
              Vt + mt * 4096 + d * 64 + (((kc * 4 + quad) ^ (d & 7)) * 8));
          oa[f] = __builtin_amdgcn_mfma_f32_16x16x32_bf16(pa[kc], bv, oa[f], 0, 0, 0);
        }
      }
    }

    // ---- epilogue: normalize, bounce through per-wave Ps, 16B stores
    #pragma unroll
    for (int r2 = 0; r2 < 4; r2++) {
      const float inv = 1.f / runsum[r2];
      const int q = quad * 4 + r2;
      #pragma unroll
      for (int f = 0; f < 4; f++)
        Ps[w][q * 64 + f * 16 + l15] = f2bf(oa[f][r2] * inv);
    }
    #pragma unroll
    for (int i = 0; i < 2; i++) {
      const int j = lane + i * 64;          // 16B chunk index 0..127
      const int q = j >> 3, c8 = j & 7;
      short8 v = *(const short8*)(&Ps[w][j * 8]);
      *(short8*)(QKV + (size_t)((qbase + q) * L_ + l) * 2304 + h * 64 + c8 * 8) = v;
    }
  }
}

// ---------------------------------------------------------------------------
__global__ __launch_bounds__(256) void score_kernel(const unsigned short* __restrict__ X,
                                                    const float* __restrict__ em,
                                                    float* __restrict__ Sv) {
  const int j = blockIdx.x;
  const int t = threadIdx.x;
  __shared__ float red[4];
  float part = 0.f;
  for (int c = 0; c < 3; c++) {
    const int d = t + c * 256;
    const unsigned short* p = X + (size_t)j * L_ * D_ + d;
    float s = 0.f;
    for (int l = 0; l < L_; l++) s += bf2f(p[l * D_]);
    const float diff = s * (1.f / 64.f) - em[j * D_ + d];
    part += diff * diff;
  }
  const float tot = blockSum256(part, red);
  if (t == 0) Sv[j] = tot;
}

// ---------------------------------------------------------------------------
__global__ __launch_bounds__(256) void finalize_kernel(const float* __restrict__ Sv,
                                                       int* __restrict__ mi,
                                                       float* __restrict__ out) {
  const int t = threadIdx.x;
  if (t < B_) {
    const int nr = mi[MI_NRESP + t];
    float best = 3.0e38f; int bi = 0;
    for (int j = 0; j < nr; j++) {
      const float v = Sv[j];
      if (v < best) { best = v; bi = j; }
    }
    mi[MI_NODE + t] = bi + 1;
    int next = nr / 20; if (next < 1) next = 1;
    out[OUT_NTL + t] = (float)(1 + next);
  }
  if (t == 0) out[OUT_NEA] = 0.f;
  __syncthreads();
  for (int idx = t; idx < B_ * T_; idx += 256) {
    const int b = idx >> 5, tt = idx & 31;
    out[OUT_OH + idx] = (tt == 0 || tt == mi[MI_NODE + b]) ? 1.f : 0.f;
  }
}

// ---------------------------------------------------------------------------
__global__ __launch_bounds__(256) void maskout_kernel(const float* __restrict__ am,
                                                      const int* __restrict__ mi,
                                                      float* __restrict__ out) {
  const int idx = blockIdx.x * 256 + threadIdx.x;
  const int b = idx >> 11, rem = idx & 2047;
  const int tt = rem >> 6, l = rem & 63;
  const int node = mi[MI_NODE + b];
  out[OUT_EXT + idx] = (tt == 0 || tt == node) ? 1.f : 0.f;
  float nm;
  if (tt == 0)      nm = am[(b * T_) * L_ + l];
  else if (tt == 1) nm = am[(b * T_ + node) * L_ + l];
  else              nm = 0.f;
  out[OUT_NMSK + idx] = nm;
}

// ---------------------------------------------------------------------------
__global__ __launch_bounds__(192) void newemb_kernel(const float* __restrict__ emb,
                                                     const int* __restrict__ mi,
                                                     float* __restrict__ out) {
  const int blk = blockIdx.x;
  const int b = blk >> 11, rem = blk & 2047;
  const int tt = rem >> 6, l = rem & 63;
  const int srct = (tt == 1) ? mi[MI_NODE + b] : 0;
  const float4 v = ((const float4*)(emb + (size_t)((b * T_ + srct) * L_ + l) * D_))[threadIdx.x];
  float* dst = out + OUT_NEMB + (size_t)blk * D_ + threadIdx.x * 4;
  dst[0] = v.x; dst[1] = v.y; dst[2] = v.z; dst[3] = v.w;
}

// ===========================================================================
extern "C" void kernel_launch(void* const* d_in, const int* in_sizes, int n_in,
                              void* d_out, int out_size, void* d_ws, size_t ws_size,
                              hipStream_t stream) {
  (void)in_sizes; (void)n_in; (void)out_size; (void)ws_size;
  const int*   tl  = (const int*)d_in[0];
  const float* emb = (const float*)d_in[1];
  const float* am  = (const float*)d_in[2];
  const float* P[28];
  for (int i = 0; i < 28; i++) P[i] = (const float*)d_in[3 + i];

  float* wsf   = (float*)d_ws;
  int*   mi    = (int*)d_ws;
  float* bias2 = wsf + WS_BIAS2;
  float* emean = wsf + WS_EMEAN;
  float* Sv    = wsf + WS_S;
  unsigned short* Wst = (unsigned short*)(wsf + WS_WST);
  unsigned short* BIG = (unsigned short*)(wsf + WS_BIG);
  float* Zb    = wsf + WS_BIG;                      // fp32 Z overlay (enc->dec)
  float* out   = (float*)d_out;
  unsigned short* X = (unsigned short*)(out + OUT_XSCR);  // bf16 residual

  meta_kernel<<<1, 64, 0, stream>>>(tl, mi);
  gather_kernel<<<NP_ * L_, 192, 0, stream>>>(emb, am, mi, X, bias2);
  emean_kernel<<<NP_, 256, 0, stream>>>(X, emean);

  const int RT = NP_ * 64 / 128;   // 256 row tiles
  const int LNB = NP_ * L_ / 4;    // 8192 ln blocks (4 rows each)
  for (int s = 0; s < 2; s++) {
    const float* const* q = P + s * 12;
    for (int i = 0; i < 2; i++) {
      // QKV: X -> BIG [rows, 2304]
      w2bf_kernel<<<(3 * D_ * D_) / 1024, 256, 0, stream>>>(q[0] + (size_t)i * 3 * D_ * D_, Wst);
      gemm_mfma<0, false><<<dim3(RT, 18), 256, 0, stream>>>(
          X, D_, D_, Wst, D_, q[1] + i * 3 * D_, BIG, 3 * D_, mi);
      attn_kernel<<<dim3(L_, H_), 512, 0, stream>>>(BIG, bias2, mi);
      // out-proj: O (Q cols of BIG, lda=2304) -> += X
      w2bf_kernel<<<(D_ * D_) / 1024, 256, 0, stream>>>(q[2] + (size_t)i * D_ * D_, Wst);
      gemm_mfma<0, true><<<dim3(RT, 6), 256, 0, stream>>>(
          BIG, 3 * D_, D_, Wst, D_, q[3] + i * D_, X, D_, mi);
      ln_kernel<<<LNB, 256, 0, stream>>>(X, q[4] + i * D_, q[5] + i * D_, mi);
      // FFN1: X -> hidden BIG [rows, 2048] (relu)
      w2bf_kernel<<<(F_ * D_) / 1024, 256, 0, stream>>>(q[6] + (size_t)i * F_ * D_, Wst);
      gemm_mfma<1, false><<<dim3(RT, 16), 256, 0, stream>>>(
          X, D_, D_, Wst, D_, q[7] + i * F_, BIG, F_, mi);
      // FFN2: hidden -> += X
      w2bf_kernel<<<(D_ * F_) / 1024, 256, 0, stream>>>(q[8] + (size_t)i * D_ * F_, Wst);
      gemm_mfma<0, true><<<dim3(RT, 6), 256, 0, stream>>>(
          BIG, F_, F_, Wst, F_, q[9] + i * D_, X, D_, mi);
      ln_kernel<<<LNB, 256, 0, stream>>>(X, q[10] + i * D_, q[11] + i * D_, mi);
    }
    if (s == 0) {
      // z = tanh(h @ pe_w^T + pe_b) -> Z fp32 (stride 128, cols 100..127 = 0)
      gemm_kernel<2, 1, 0><<<dim3(NP_, 2), 256, 0, stream>>>(
          X, D_, D_, P[24], D_, ZR_, P[25], Zb, ZP_, mi);
      // zd = tanh(z @ pd_w^T + pd_b) -> X bf16 (decoder input)
      gemm_kernel<2, 0, 1><<<dim3(NP_, 12), 256, 0, stream>>>(
          Zb, ZP_, ZP_, P[26], ZR_, D_, P[27], X, D_, mi);
    }
  }

  score_kernel<<<NP_, 256, 0, stream>>>(X, emean, Sv);
  finalize_kernel<<<1, 256, 0, stream>>>(Sv, mi, out);
  maskout_kernel<<<128, 256, 0, stream>>>(am, mi, out);
  newemb_kernel<<<B_ * T_ * L_, 192, 0, stream>>>(emb, mi, out);
}

// Round 5
// 2376.422 us; speedup vs baseline: 1.0527x; 1.0527x over previous
//
#include <hip/hip_runtime.h>
#include <hip/hip_bf16.h>
#include <math.h>

// ============================================================================
// ResponseFilter — round 7: 256x256 8-wave GEMM (128x64 wave tiles).
//
// Round-6 post-mortem: counted vmcnt was NEUTRAL (MfmaUtil stuck 24.5%,
// VALUBusy 43->21) -> not latency-bound; the 64x64 wave tile is LDS-BW /
// frag-read bound (16 MFMA per 8 ds_read_b128 = ratio 2.0). This round:
// 256x256 block, 512 thr = 8 waves (2x4), wave tile 128x64 -> 32 MFMA per
// 12 reads (ratio 2.67, +33%) and half the per-FLOP staging traffic
// (m198-vs-m103 geometry step, +28% measured there). Keeps the round-6
// 3-buffer counted-vmcnt skeleton (4 loads/thread/stage -> vmcnt(4)).
// Compute holds 4 B-frags resident, streams 8 A-frags (caps VGPR ~190).
// Epilogue: two 64x64 passes through per-wave LDS slices, coalesced
// short8 stores (+residual add at readback for ADD).
// Attention (KV-resident), LN (wave-per-row), everything else unchanged.
// ============================================================================

#define B_  16
#define T_  32
#define L_  64
#define D_  768
#define H_  12
#define F_  2048
#define ZR_ 100
#define ZP_ 128
#define NP_ 512
#define EPS_ 1e-5f

// meta int offsets (d_ws as int*)
#define MI_NTOT  0
#define MI_NRESP 8
#define MI_OFF   32
#define MI_BIDX  64
#define MI_TIDX  576
#define MI_NODE  1088

// ws float offsets
#define WS_BIAS2 2048
#define WS_EMEAN 34816
#define WS_S     428032
#define WS_WST   428544    // bf16 weight stage, 1,769,472 ushorts (3.54 MB)
#define WS_BIG   1313280   // bf16 QKV/hidden region; fp32 Z overlay

// d_out float offsets (flat tuple: oh[512], ext_mask[32768], n_ext_adv[1],
// new_tree_lens[16], new_emb[25165824], new_msk[32768])
#define OUT_OH   0
#define OUT_EXT  512
#define OUT_NEA  33280
#define OUT_NTL  33281
#define OUT_NEMB 33297
#define OUT_NMSK 25199121
#define OUT_XSCR 33300   // bf16 X scratch (16B aligned), 32768*768 ushorts

typedef __attribute__((ext_vector_type(8))) short short8;
typedef __attribute__((ext_vector_type(4))) float f32x4;

__device__ inline float bf2f(unsigned s) {
  return __uint_as_float((s & 0xffffu) << 16);
}
__device__ inline unsigned short f2bf(float x) {
  unsigned u = __float_as_uint(x);
  u += 0x7fffu + ((u >> 16) & 1u);      // round-to-nearest-even
  return (unsigned short)(u >> 16);
}
__device__ inline unsigned pack2(float a, float b) {
  return (unsigned)f2bf(a) | ((unsigned)f2bf(b) << 16);
}

// ---------------------------------------------------------------------------
__global__ void meta_kernel(const int* __restrict__ tl, int* __restrict__ mi) {
  if (threadIdx.x != 0) return;
  int off = 0;
  for (int b = 0; b < B_; b++) {
    int nr = tl[b] - 1;
    mi[MI_NRESP + b] = nr;
    mi[MI_OFF + b] = off;
    off += nr;
  }
  mi[MI_NTOT] = off;
  for (int j = 0; j < NP_; j++) {
    int b = -1, t = 0;
    if (j < off) {
      b = 0;
      while (b + 1 < B_ && j >= mi[MI_OFF + b + 1]) b++;
      t = j - mi[MI_OFF + b] + 1;
    }
    mi[MI_BIDX + j] = b;
    mi[MI_TIDX + j] = t;
  }
}

// ---------------------------------------------------------------------------
// fp32 -> bf16 weight conversion (n multiple of 1024)
__global__ __launch_bounds__(256) void w2bf_kernel(const float* __restrict__ W,
                                                   unsigned short* __restrict__ o) {
  const int i = (blockIdx.x * 256 + threadIdx.x) * 4;
  float4 v = *(const float4*)(W + i);
  uint2 pk; pk.x = pack2(v.x, v.y); pk.y = pack2(v.z, v.w);
  *(uint2*)(o + i) = pk;
}

// ---------------------------------------------------------------------------
// X[j,l,:] bf16 = reply embedding (zero for padded j); bias2 = mask or -1e30
__global__ __launch_bounds__(192) void gather_kernel(
    const float* __restrict__ emb, const float* __restrict__ am,
    const int* __restrict__ mi, unsigned short* __restrict__ X,
    float* __restrict__ bias2) {
  const int blk = blockIdx.x;          // j*64 + l
  const int j = blk >> 6, l = blk & 63;
  const int ntot = mi[MI_NTOT];
  const int t = threadIdx.x;
  float4 v = make_float4(0.f, 0.f, 0.f, 0.f);
  if (j < ntot) {
    const int b = mi[MI_BIDX + j], tt = mi[MI_TIDX + j];
    v = ((const float4*)(emb + (size_t)((b * T_ + tt) * L_ + l) * D_))[t];
    if (t == 0) bias2[blk] = am[(b * T_ + tt) * L_ + l];
  } else {
    if (t == 0) bias2[blk] = -1e30f;
  }
  uint2 pk; pk.x = pack2(v.x, v.y); pk.y = pack2(v.z, v.w);
  *(uint2*)(X + (size_t)blk * D_ + t * 4) = pk;
}

// ---------------------------------------------------------------------------
__global__ __launch_bounds__(256) void emean_kernel(const unsigned short* __restrict__ X,
                                                    float* __restrict__ em) {
  const int j = blockIdx.x;
  int d = threadIdx.x;
  for (int c = 0; c < 3; c++, d += 256) {
    const unsigned short* p = X + (size_t)j * L_ * D_ + d;
    float s = 0.f;
    for (int l = 0; l < L_; l++) s += bf2f(p[l * D_]);
    em[j * D_ + d] = s * (1.f / 64.f);
  }
}

// ---------------------------------------------------------------------------
__device__ inline float blockSum256(float v, float* red) {
  #pragma unroll
  for (int o = 32; o > 0; o >>= 1) v += __shfl_down(v, o);
  const int lane = threadIdx.x & 63, wid = threadIdx.x >> 6;
  __syncthreads();
  if (lane == 0) red[wid] = v;
  __syncthreads();
  return red[0] + red[1] + red[2] + red[3];
}

// in-place LN, wave-per-row (4 rows/block, no barriers); skips padded rows
__global__ __launch_bounds__(256) void ln_kernel(unsigned short* __restrict__ X,
                                                 const float* __restrict__ g,
                                                 const float* __restrict__ bb,
                                                 const int* __restrict__ mi) {
  const int row = blockIdx.x * 4 + (threadIdx.x >> 6);
  if (row >= mi[MI_NTOT] * L_) return;
  const int lane = threadIdx.x & 63;
  unsigned short* p = X + (size_t)row * D_;
  float v[12];
  #pragma unroll
  for (int c = 0; c < 3; c++) {
    uint2 u = *(const uint2*)(p + lane * 4 + c * 256);
    v[c * 4 + 0] = bf2f(u.x); v[c * 4 + 1] = bf2f(u.x >> 16);
    v[c * 4 + 2] = bf2f(u.y); v[c * 4 + 3] = bf2f(u.y >> 16);
  }
  float s = 0.f;
  #pragma unroll
  for (int i = 0; i < 12; i++) s += v[i];
  #pragma unroll
  for (int o = 32; o > 0; o >>= 1) s += __shfl_xor(s, o);
  const float m = s * (1.f / 768.f);
  float q = 0.f;
  #pragma unroll
  for (int i = 0; i < 12; i++) { v[i] -= m; q += v[i] * v[i]; }
  #pragma unroll
  for (int o = 32; o > 0; o >>= 1) q += __shfl_xor(q, o);
  const float r = rsqrtf(q * (1.f / 768.f) + EPS_);
  #pragma unroll
  for (int c = 0; c < 3; c++) {
    const int d = lane * 4 + c * 256;
    float4 gv = *(const float4*)(g + d);
    float4 bv = *(const float4*)(bb + d);
    uint2 pk;
    pk.x = pack2(v[c * 4 + 0] * r * gv.x + bv.x, v[c * 4 + 1] * r * gv.y + bv.y);
    pk.y = pack2(v[c * 4 + 2] * r * gv.z + bv.z, v[c * 4 + 3] * r * gv.w + bv.w);
    *(uint2*)(p + d) = pk;
  }
}

// ---------------------------------------------------------------------------
// MFMA bf16 GEMM: C[M,N] = [C +] act(A @ W^T + bias). 256x256 tile, 512 thr
// (8 waves 2x4, each 128x64 via 8x4 of 16x16x32 MFMA). K mult of 32, N mult
// of 256. Counted-vmcnt pipeline: 3 LDS buffers (96 KB), 2 stages in flight;
// per K-step: {s_waitcnt vmcnt(4); s_barrier} -> STAGE(i+2) -> COMPUTE(i).
// stage(i+2) targets buf[(i-1)%3], whose readers precede barrier(i) ->
// race-free with ONE barrier per step.
// LDS k-group XOR swizzle: slot (row, sp) holds kg = sp ^ ((row>>1)&3).
// Epilogue: two 64x64 passes via per-wave 8KB LDS slice -> coalesced short8
// stores (+ residual add at readback for ADD).
template <int ACT, bool ADD>
__global__ __launch_bounds__(512) void gemm_mfma(
    const unsigned short* __restrict__ A, int lda, int K,
    const unsigned short* __restrict__ W, int ldw,
    const float* __restrict__ bias,
    unsigned short* __restrict__ C, int ldc,
    const int* __restrict__ mi) {
  const int rows = mi[MI_NTOT] * 64;
  const int row0 = blockIdx.x * 256;
  if (row0 >= rows) return;
  const int col0 = blockIdx.y * 256;
  __shared__ unsigned short Sh[6 * 8192];   // 3 A bufs + 3 B bufs (96 KB)
  unsigned short* SA = Sh;
  unsigned short* SB = Sh + 3 * 8192;
  const int t = threadIdx.x;
  const int lane = t & 63, w = t >> 6;        // 8 waves
  const int wr = w >> 2, wc = w & 3;          // 2x4 wave grid, tile 128x64
  const int quad = lane >> 4, l15 = lane & 15;
  f32x4 acc[8][4];
  #pragma unroll
  for (int i = 0; i < 8; i++)
    #pragma unroll
    for (int j = 0; j < 4; j++) acc[i][j] = (f32x4){0.f, 0.f, 0.f, 0.f};

  // per-lane staging coords (2 chunks per wave per tile, per matrix;
  // chunk = 64 lanes x 16B = 1KB; 16 chunks cover 256 rows x 32 k)
  int schunk[2];
  const unsigned short* gA[2];
  const unsigned short* gB[2];
  #pragma unroll
  for (int r = 0; r < 2; r++) {
    const int c = r * 8 + w;
    const int g = c * 64 + lane;
    const int row = g >> 2, slot = g & 3;
    const int kg = slot ^ ((row >> 1) & 3);
    schunk[r] = c;
    gA[r] = A + (size_t)(row0 + row) * lda + kg * 8;
    gB[r] = W + (size_t)(col0 + row) * ldw + kg * 8;
  }
  // fragment LDS offsets (ushorts)
  int aoff[8], boff[4];
  #pragma unroll
  for (int m = 0; m < 8; m++) {
    const int ar = wr * 128 + m * 16 + l15;
    aoff[m] = ar * 32 + (quad ^ ((ar >> 1) & 3)) * 8;
  }
  #pragma unroll
  for (int n = 0; n < 4; n++) {
    const int bn = wc * 64 + n * 16 + l15;
    boff[n] = bn * 32 + (quad ^ ((bn >> 1) & 3)) * 8;
  }

#define STAGE_(bi_, kk_)                                                       \
  { const int _off = (bi_) * 8192;                                             \
    _Pragma("unroll")                                                          \
    for (int r = 0; r < 2; r++) {                                              \
      __builtin_amdgcn_global_load_lds(                                        \
          (const __attribute__((address_space(1))) void*)(gA[r] + (kk_)),      \
          (__attribute__((address_space(3))) void*)(SA + _off + schunk[r] * 512), \
          16, 0, 0);                                                           \
      __builtin_amdgcn_global_load_lds(                                        \
          (const __attribute__((address_space(1))) void*)(gB[r] + (kk_)),      \
          (__attribute__((address_space(3))) void*)(SB + _off + schunk[r] * 512), \
          16, 0, 0);                                                           \
    } }

#define COMPUTE_(bi_)                                                          \
  {                                                                            \
    const int _off = (bi_) * 8192;                                             \
    short8 bfr[4];                                                             \
    _Pragma("unroll")                                                          \
    for (int n = 0; n < 4; n++) bfr[n] = *(const short8*)(SB + _off + boff[n]); \
    _Pragma("unroll")                                                          \
    for (int m = 0; m < 8; m++) {                                              \
      short8 afm = *(const short8*)(SA + _off + aoff[m]);                      \
      _Pragma("unroll")                                                        \
      for (int n = 0; n < 4; n++)                                              \
        acc[m][n] = __builtin_amdgcn_mfma_f32_16x16x32_bf16(afm, bfr[n],       \
                                                            acc[m][n], 0, 0, 0); \
    }                                                                          \
  }

  const int NS = K >> 5;     // K-steps of 32 (all call sites have NS >= 3)
  STAGE_(0, 0);
  STAGE_(1, 32);
  int bi = 0;
  for (int i = 0; i < NS; i++) {
    if (i + 1 < NS) {
      asm volatile("s_waitcnt vmcnt(4)\ns_barrier" ::: "memory");
    } else {
      asm volatile("s_waitcnt vmcnt(0)\ns_barrier" ::: "memory");
    }
    __builtin_amdgcn_sched_barrier(0);
    if (i + 2 < NS) {
      const int b2 = (bi >= 1) ? bi - 1 : 2;   // (i+2)%3
      STAGE_(b2, (i + 2) * 32);
    }
    COMPUTE_(bi);
    bi = (bi >= 2) ? 0 : bi + 1;
  }
  __syncthreads();           // LDS now dead -> reuse as epilogue bounce

#undef STAGE_
#undef COMPUTE_

  // epilogue: C/D layout col = lane&15, row = quad*4 + reg. Two 64x64 passes
  // per wave through its private 8KB slice, then coalesced short8 stores
  // (8 per lane per pass). Residual add (ADD) at readback.
  unsigned short* slice = Sh + w * 4096;
  float bv[4];
  #pragma unroll
  for (int n = 0; n < 4; n++) bv[n] = bias[col0 + wc * 64 + n * 16 + l15];
  #pragma unroll
  for (int p = 0; p < 2; p++) {
    #pragma unroll
    for (int mm = 0; mm < 4; mm++) {
      #pragma unroll
      for (int reg = 0; reg < 4; reg++) {
        const int r64 = mm * 16 + quad * 4 + reg;
        #pragma unroll
        for (int n = 0; n < 4; n++) {
          float x = acc[p * 4 + mm][n][reg] + bv[n];
          if (ACT == 1) x = fmaxf(x, 0.f);
          slice[r64 * 64 + n * 16 + l15] = f2bf(x);
        }
      }
    }
    unsigned short* crow =
        C + (size_t)(row0 + wr * 128 + p * 64) * ldc + col0 + wc * 64;
    #pragma unroll
    for (int i = 0; i < 8; i++) {
      const int j = i * 64 + lane;           // 16B chunk 0..511 of 64x64 tile
      const int r64 = j >> 3, c8 = (j & 7) * 8;
      short8 v = *(const short8*)(slice + j * 8);
      unsigned short* cp = crow + (size_t)r64 * ldc + c8;
      if (ADD) {
        short8 cv = *(const short8*)cp;
        #pragma unroll
        for (int e = 0; e < 8; e++)
          v[e] = (short)f2bf(bf2f((unsigned short)v[e]) +
                             bf2f((unsigned short)cv[e]));
      }
      *(short8*)cp = v;
    }
  }
}

// ---------------------------------------------------------------------------
// VALU GEMM (kept for ragged pe/pd only): C = act(A @ W^T + b)
// AT: 0 fp32 A, 1 bf16 A.  CT: 0 fp32 C, 1 bf16 C.
template <int ACT, int AT, int CT>
__global__ __launch_bounds__(256) void gemm_kernel(
    const void* __restrict__ Av, int lda, int kloop,
    const float* __restrict__ W, int kw, int nreal,
    const float* __restrict__ bias,
    void* __restrict__ Cv, int ldc,
    const int* __restrict__ mi) {
  if ((int)blockIdx.x >= mi[MI_NTOT]) return;
  __shared__ float As[16][68];
  __shared__ float Ws[16][68];
  const int t = threadIdx.x;
  const int tx = t & 15, ty = t >> 4;
  const int lrow = t >> 2, lkg = (t & 3) * 4;
  const size_t row0 = (size_t)blockIdx.x * 64;
  const int col0 = blockIdx.y * 64;
  float acc[4][4] = {};
  for (int k0 = 0; k0 < kloop; k0 += 16) {
    float a4[4];
    if (AT == 0) {
      float4 av = *(const float4*)((const float*)Av + (row0 + lrow) * (size_t)lda + k0 + lkg);
      a4[0] = av.x; a4[1] = av.y; a4[2] = av.z; a4[3] = av.w;
    } else {
      uint2 u = *(const uint2*)((const unsigned short*)Av + (row0 + lrow) * (size_t)lda + k0 + lkg);
      a4[0] = bf2f(u.x); a4[1] = bf2f(u.x >> 16);
      a4[2] = bf2f(u.y); a4[3] = bf2f(u.y >> 16);
    }
    float wv[4];
    const int wn = col0 + lrow;
    #pragma unroll
    for (int i = 0; i < 4; i++) {
      const int k = k0 + lkg + i;
      wv[i] = (wn < nreal && k < kw) ? W[(size_t)wn * kw + k] : 0.f;
    }
    __syncthreads();
    As[lkg + 0][lrow] = a4[0]; As[lkg + 1][lrow] = a4[1];
    As[lkg + 2][lrow] = a4[2]; As[lkg + 3][lrow] = a4[3];
    Ws[lkg + 0][lrow] = wv[0]; Ws[lkg + 1][lrow] = wv[1];
    Ws[lkg + 2][lrow] = wv[2]; Ws[lkg + 3][lrow] = wv[3];
    __syncthreads();
    #pragma unroll
    for (int kk = 0; kk < 16; kk++) {
      float4 av4 = *(const float4*)(&As[kk][ty * 4]);
      float4 wv4 = *(const float4*)(&Ws[kk][tx * 4]);
      float aa[4] = {av4.x, av4.y, av4.z, av4.w};
      float ww[4] = {wv4.x, wv4.y, wv4.z, wv4.w};
      #pragma unroll
      for (int i = 0; i < 4; i++)
        #pragma unroll
        for (int j = 0; j < 4; j++) acc[i][j] += aa[i] * ww[j];
    }
  }
  const int n0 = col0 + tx * 4;
  float bv[4];
  #pragma unroll
  for (int j = 0; j < 4; j++) bv[j] = (n0 + j < nreal) ? bias[n0 + j] : 0.f;
  #pragma unroll
  for (int i = 0; i < 4; i++) {
    float v[4];
    #pragma unroll
    for (int j = 0; j < 4; j++) {
      float x = acc[i][j] + bv[j];
      if (ACT == 1) x = fmaxf(x, 0.f);
      if (ACT == 2) x = tanhf(x);
      v[j] = x;
    }
    if (CT == 0) {
      float* cp = (float*)Cv + (row0 + ty * 4 + i) * (size_t)ldc + n0;
      *(float4*)cp = make_float4(v[0], v[1], v[2], v[3]);
    } else {
      unsigned short* cp = (unsigned short*)Cv + (row0 + ty * 4 + i) * (size_t)ldc + n0;
      uint2 pk; pk.x = pack2(v[0], v[1]); pk.y = pack2(v[2], v[3]);
      *(uint2*)cp = pk;
    }
  }
}

// ---------------------------------------------------------------------------
// MFMA attention, KV-resident: one block per (l, h), 8 waves (512 thr).
// Stage ALL K (global_load_lds, pre-swizzled source -> linear LDS) and V^T
// (manual transpose scatter) once; single barrier; then each wave free-runs
// q-tiles (16 rows/wave, 128/block) x kv-tiles with zero global loads and
// zero barriers (P staging per-wave). O bf16 overwrites Q columns of QKV
// (disjoint from staged K/V columns; each wave owns its rows -> race-free).
// LDS tile swizzle: elem(row,col) at row*64 + ((col>>3)^(row&7))*8 + (col&7).
__global__ __launch_bounds__(512) void attn_kernel(
    unsigned short* __restrict__ QKV, const float* __restrict__ bias2,
    const int* __restrict__ mi) {
  const int ntot = mi[MI_NTOT];
  const int l = blockIdx.x, h = blockIdx.y;
  const int ntk = (ntot + 63) >> 6;     // kv tiles (padded keys masked by bias)
  __shared__ unsigned short Ks[512 * 64];   // K rows [m][d], swizzled
  __shared__ unsigned short Vt[8 * 4096];   // per-tile V^T [d][m], swizzled
  __shared__ unsigned short Ps[8][1024];    // per-wave P / O-bounce
  __shared__ float bs[512];                 // bias column for this l
  const int t = threadIdx.x;
  const int lane = t & 63, w = t >> 6;
  const int quad = lane >> 4, l15 = lane & 15;

  // ---- stage K: linear LDS dst, source chunk pre-swizzled so slot g of row
  // m holds chunk g ^ (m&7) (matches the ds_read swizzle below)
  {
    const int sub = lane >> 3;              // low 3 bits of m
    const int cc = (lane & 7) ^ sub;        // source chunk for this slot
    for (int it = 0; it < ntk; it++) {
      const int m = it * 64 + w * 8 + sub;
      const unsigned short* src =
          QKV + (size_t)(m * L_ + l) * 2304 + 768 + h * 64 + cc * 8;
      __builtin_amdgcn_global_load_lds(
          (const __attribute__((address_space(1))) void*)src,
          (__attribute__((address_space(3))) void*)(Ks + it * 4096 + w * 512),
          16, 0, 0);
    }
  }
  // ---- stage V transposed: thread t -> m = t&63, d in [(t>>6)*8, +8)
  {
    const int m = t & 63;
    const int d0 = (t >> 6) * 8;
    for (int mt = 0; mt < ntk; mt++) {
      short8 v = *(const short8*)(
          QKV + (size_t)((mt * 64 + m) * L_ + l) * 2304 + 1536 + h * 64 + d0);
      #pragma unroll
      for (int i = 0; i < 8; i++) {
        const int d = d0 + i;
        Vt[mt * 4096 + d * 64 + (((m >> 3) ^ (d & 7)) * 8) + (m & 7)] =
            (unsigned short)v[i];
      }
    }
  }
  // ---- stage bias column (padded m already -1e30 from gather)
  bs[t] = bias2[t * 64 + l];
  __syncthreads();

  const int nqt = (ntot + 127) >> 7;
  for (int qt = 0; qt < nqt; qt++) {
    const int qbase = qt * 128 + w * 16;
    if (qbase >= ntot) continue;

    // Q A-frags direct from global (2 x 16B per lane)
    short8 af[2];
    #pragma unroll
    for (int kc = 0; kc < 2; kc++)
      af[kc] = *(const short8*)(
          QKV + (size_t)((qbase + l15) * L_ + l) * 2304 + h * 64 + (kc * 4 + quad) * 8);

    f32x4 oa[4];
    float runmax[4], runsum[4];
    #pragma unroll
    for (int f = 0; f < 4; f++) oa[f] = (f32x4){0.f, 0.f, 0.f, 0.f};
    #pragma unroll
    for (int r2 = 0; r2 < 4; r2++) { runmax[r2] = -3.0e38f; runsum[r2] = 0.f; }

    for (int mt = 0; mt < ntk; mt++) {
      // ---- S = Q @ K^T  (C layout: row q = quad*4+reg, col m = cb*16+l15)
      f32x4 sv[4];
      #pragma unroll
      for (int cb = 0; cb < 4; cb++) {
        sv[cb] = (f32x4){0.f, 0.f, 0.f, 0.f};
        const int mrow = mt * 64 + cb * 16 + l15;
        #pragma unroll
        for (int kc = 0; kc < 2; kc++) {
          short8 bk = *(const short8*)(
              Ks + mrow * 64 + (((kc * 4 + quad) ^ (mrow & 7)) * 8));
          sv[cb] = __builtin_amdgcn_mfma_f32_16x16x32_bf16(af[kc], bk, sv[cb], 0, 0, 0);
        }
      }

      // ---- online softmax (state per q-row = quad*4+reg)
      float bj[4];
      #pragma unroll
      for (int cb = 0; cb < 4; cb++) bj[cb] = bs[mt * 64 + cb * 16 + l15];
      float pj[4][4];   // [cb][reg]
      #pragma unroll
      for (int cb = 0; cb < 4; cb++)
        #pragma unroll
        for (int r2 = 0; r2 < 4; r2++) pj[cb][r2] = sv[cb][r2] * 0.125f + bj[cb];
      float tmax[4];
      #pragma unroll
      for (int r2 = 0; r2 < 4; r2++)
        tmax[r2] = fmaxf(fmaxf(pj[0][r2], pj[1][r2]), fmaxf(pj[2][r2], pj[3][r2]));
      #pragma unroll
      for (int o2 = 1; o2 < 16; o2 <<= 1)
        #pragma unroll
        for (int r2 = 0; r2 < 4; r2++) tmax[r2] = fmaxf(tmax[r2], __shfl_xor(tmax[r2], o2));
      float tsum[4];
      #pragma unroll
      for (int r2 = 0; r2 < 4; r2++) {
        const float nmax = fmaxf(runmax[r2], tmax[r2]);
        const float alpha = __expf(runmax[r2] - nmax);
        runmax[r2] = nmax;
        float s0 = 0.f;
        #pragma unroll
        for (int cb = 0; cb < 4; cb++) { pj[cb][r2] = __expf(pj[cb][r2] - nmax); s0 += pj[cb][r2]; }
        tsum[r2] = s0;
        runsum[r2] *= alpha;
        #pragma unroll
        for (int f = 0; f < 4; f++) oa[f][r2] *= alpha;
      }
      #pragma unroll
      for (int o2 = 1; o2 < 16; o2 <<= 1)
        #pragma unroll
        for (int r2 = 0; r2 < 4; r2++) tsum[r2] += __shfl_xor(tsum[r2], o2);
      #pragma unroll
      for (int r2 = 0; r2 < 4; r2++) runsum[r2] += tsum[r2];

      // ---- P -> per-wave LDS (A-operand layout, bf16)
      #pragma unroll
      for (int cb = 0; cb < 4; cb++) {
        const int m = cb * 16 + l15;
        #pragma unroll
        for (int r2 = 0; r2 < 4; r2++) {
          const int q = quad * 4 + r2;
          Ps[w][q * 64 + (((m >> 3) ^ (q & 7)) * 8) + (m & 7)] = f2bf(pj[cb][r2]);
        }
      }
      // ---- O += P @ V
      short8 pa[2];
      #pragma unroll
      for (int kc = 0; kc < 2; kc++)
        pa[kc] = *(const short8*)(
            &Ps[w][l15 * 64 + (((kc * 4 + quad) ^ (l15 & 7)) * 8)]);
      #pragma unroll
      for (int f = 0; f < 4; f++) {
        const int d = f * 16 + l15;
        #pragma unroll
        for (int kc = 0; kc < 2; kc++) {
          short8 bv = *(const short8*)(
              Vt + mt * 4096 + d * 64 + (((kc * 4 + quad) ^ (d & 7)) * 8));
          oa[f] = __builtin_amdgcn_mfma_f32_16x16x32_bf16(pa[kc], bv, oa[f], 0, 0, 0);
        }
      }
    }

    // ---- epilogue: normalize, bounce through per-wave Ps, 16B stores
    #pragma unroll
    for (int r2 = 0; r2 < 4; r2++) {
      const float inv = 1.f / runsum[r2];
      const int q = quad * 4 + r2;
      #pragma unroll
      for (int f = 0; f < 4; f++)
        Ps[w][q * 64 + f * 16 + l15] = f2bf(oa[f][r2] * inv);
    }
    #pragma unroll
    for (int i = 0; i < 2; i++) {
      const int j = lane + i * 64;          // 16B chunk index 0..127
      const int q = j >> 3, c8 = j & 7;
      short8 v = *(const short8*)(&Ps[w][j * 8]);
      *(short8*)(QKV + (size_t)((qbase + q) * L_ + l) * 2304 + h * 64 + c8 * 8) = v;
    }
  }
}

// ---------------------------------------------------------------------------
__global__ __launch_bounds__(256) void score_kernel(const unsigned short* __restrict__ X,
                                                    const float* __restrict__ em,
                                                    float* __restrict__ Sv) {
  const int j = blockIdx.x;
  const int t = threadIdx.x;
  __shared__ float red[4];
  float part = 0.f;
  for (int c = 0; c < 3; c++) {
    const int d = t + c * 256;
    const unsigned short* p = X + (size_t)j * L_ * D_ + d;
    float s = 0.f;
    for (int l = 0; l < L_; l++) s += bf2f(p[l * D_]);
    const float diff = s * (1.f / 64.f) - em[j * D_ + d];
    part += diff * diff;
  }
  const float tot = blockSum256(part, red);
  if (t == 0) Sv[j] = tot;
}

// ---------------------------------------------------------------------------
__global__ __launch_bounds__(256) void finalize_kernel(const float* __restrict__ Sv,
                                                       int* __restrict__ mi,
                                                       float* __restrict__ out) {
  const int t = threadIdx.x;
  if (t < B_) {
    const int nr = mi[MI_NRESP + t];
    float best = 3.0e38f; int bi = 0;
    for (int j = 0; j < nr; j++) {
      const float v = Sv[j];
      if (v < best) { best = v; bi = j; }
    }
    mi[MI_NODE + t] = bi + 1;
    int next = nr / 20; if (next < 1) next = 1;
    out[OUT_NTL + t] = (float)(1 + next);
  }
  if (t == 0) out[OUT_NEA] = 0.f;
  __syncthreads();
  for (int idx = t; idx < B_ * T_; idx += 256) {
    const int b = idx >> 5, tt = idx & 31;
    out[OUT_OH + idx] = (tt == 0 || tt == mi[MI_NODE + b]) ? 1.f : 0.f;
  }
}

// ---------------------------------------------------------------------------
__global__ __launch_bounds__(256) void maskout_kernel(const float* __restrict__ am,
                                                      const int* __restrict__ mi,
                                                      float* __restrict__ out) {
  const int idx = blockIdx.x * 256 + threadIdx.x;
  const int b = idx >> 11, rem = idx & 2047;
  const int tt = rem >> 6, l = rem & 63;
  const int node = mi[MI_NODE + b];
  out[OUT_EXT + idx] = (tt == 0 || tt == node) ? 1.f : 0.f;
  float nm;
  if (tt == 0)      nm = am[(b * T_) * L_ + l];
  else if (tt == 1) nm = am[(b * T_ + node) * L_ + l];
  else              nm = 0.f;
  out[OUT_NMSK + idx] = nm;
}

// ---------------------------------------------------------------------------
__global__ __launch_bounds__(192) void newemb_kernel(const float* __restrict__ emb,
                                                     const int* __restrict__ mi,
                                                     float* __restrict__ out) {
  const int blk = blockIdx.x;
  const int b = blk >> 11, rem = blk & 2047;
  const int tt = rem >> 6, l = rem & 63;
  const int srct = (tt == 1) ? mi[MI_NODE + b] : 0;
  const float4 v = ((const float4*)(emb + (size_t)((b * T_ + srct) * L_ + l) * D_))[threadIdx.x];
  float* dst = out + OUT_NEMB + (size_t)blk * D_ + threadIdx.x * 4;
  dst[0] = v.x; dst[1] = v.y; dst[2] = v.z; dst[3] = v.w;
}

// ===========================================================================
extern "C" void kernel_launch(void* const* d_in, const int* in_sizes, int n_in,
                              void* d_out, int out_size, void* d_ws, size_t ws_size,
                              hipStream_t stream) {
  (void)in_sizes; (void)n_in; (void)out_size; (void)ws_size;
  const int*   tl  = (const int*)d_in[0];
  const float* emb = (const float*)d_in[1];
  const float* am  = (const float*)d_in[2];
  const float* P[28];
  for (int i = 0; i < 28; i++) P[i] = (const float*)d_in[3 + i];

  float* wsf   = (float*)d_ws;
  int*   mi    = (int*)d_ws;
  float* bias2 = wsf + WS_BIAS2;
  float* emean = wsf + WS_EMEAN;
  float* Sv    = wsf + WS_S;
  unsigned short* Wst = (unsigned short*)(wsf + WS_WST);
  unsigned short* BIG = (unsigned short*)(wsf + WS_BIG);
  float* Zb    = wsf + WS_BIG;                      // fp32 Z overlay (enc->dec)
  float* out   = (float*)d_out;
  unsigned short* X = (unsigned short*)(out + OUT_XSCR);  // bf16 residual

  meta_kernel<<<1, 64, 0, stream>>>(tl, mi);
  gather_kernel<<<NP_ * L_, 192, 0, stream>>>(emb, am, mi, X, bias2);
  emean_kernel<<<NP_, 256, 0, stream>>>(X, emean);

  const int RTM = NP_ * 64 / 256;  // 128 row tiles (256 rows each)
  const int LNB = NP_ * L_ / 4;    // 8192 ln blocks (4 rows each)
  for (int s = 0; s < 2; s++) {
    const float* const* q = P + s * 12;
    for (int i = 0; i < 2; i++) {
      // QKV: X -> BIG [rows, 2304]
      w2bf_kernel<<<(3 * D_ * D_) / 1024, 256, 0, stream>>>(q[0] + (size_t)i * 3 * D_ * D_, Wst);
      gemm_mfma<0, false><<<dim3(RTM, 9), 512, 0, stream>>>(
          X, D_, D_, Wst, D_, q[1] + i * 3 * D_, BIG, 3 * D_, mi);
      attn_kernel<<<dim3(L_, H_), 512, 0, stream>>>(BIG, bias2, mi);
      // out-proj: O (Q cols of BIG, lda=2304) -> += X
      w2bf_kernel<<<(D_ * D_) / 1024, 256, 0, stream>>>(q[2] + (size_t)i * D_ * D_, Wst);
      gemm_mfma<0, true><<<dim3(RTM, 3), 512, 0, stream>>>(
          BIG, 3 * D_, D_, Wst, D_, q[3] + i * D_, X, D_, mi);
      ln_kernel<<<LNB, 256, 0, stream>>>(X, q[4] + i * D_, q[5] + i * D_, mi);
      // FFN1: X -> hidden BIG [rows, 2048] (relu)
      w2bf_kernel<<<(F_ * D_) / 1024, 256, 0, stream>>>(q[6] + (size_t)i * F_ * D_, Wst);
      gemm_mfma<1, false><<<dim3(RTM, 8), 512, 0, stream>>>(
          X, D_, D_, Wst, D_, q[7] + i * F_, BIG, F_, mi);
      // FFN2: hidden -> += X
      w2bf_kernel<<<(D_ * F_) / 1024, 256, 0, stream>>>(q[8] + (size_t)i * D_ * F_, Wst);
      gemm_mfma<0, true><<<dim3(RTM, 3), 512, 0, stream>>>(
          BIG, F_, F_, Wst, F_, q[9] + i * D_, X, D_, mi);
      ln_kernel<<<LNB, 256, 0, stream>>>(X, q[10] + i * D_, q[11] + i * D_, mi);
    }
    if (s == 0) {
      // z = tanh(h @ pe_w^T + pe_b) -> Z fp32 (stride 128, cols 100..127 = 0)
      gemm_kernel<2, 1, 0><<<dim3(NP_, 2), 256, 0, stream>>>(
          X, D_, D_, P[24], D_, ZR_, P[25], Zb, ZP_, mi);
      // zd = tanh(z @ pd_w^T + pd_b) -> X bf16 (decoder input)
      gemm_kernel<2, 0, 1><<<dim3(NP_, 12), 256, 0, stream>>>(
          Zb, ZP_, ZP_, P[26], ZR_, D_, P[27], X, D_, mi);
    }
  }

  score_kernel<<<NP_, 256, 0, stream>>>(X, emean, Sv);
  finalize_kernel<<<1, 256, 0, stream>>>(Sv, mi, out);
  maskout_kernel<<<128, 256, 0, stream>>>(am, mi, out);
  newemb_kernel<<<B_ * T_ * L_, 192, 0, stream>>>(emb, mi, out);
}

// Round 6
// 2302.034 us; speedup vs baseline: 1.0867x; 1.0323x over previous
//
#include <hip/hip_runtime.h>
#include <hip/hip_bf16.h>
#include <math.h>

// ============================================================================
// ResponseFilter — round 8: 8-phase GEMM schedule (T3+T4+T5, m201 template).
//
// Round-7 post-mortem: 256^2 geometry alone was +3% (MfmaUtil 21%, all pipes
// idle) — reproduces the catalog regime-gate: counted-vmcnt/swizzle/setprio
// are NULL outside the 8-phase schedule. This round ports the 8-phase
// template onto the same 256^2 / 8-wave / 128x64-wave-tile geometry:
//   - BK=64, 2 LDS K-tile dbufs (128 KB), 4 phases/K-tile.
//   - Per phase: stage 1 half-tile (2 gload_lds/thread) || ds_read subtile
//     -> s_barrier -> lgkmcnt(0)+sched_barrier(0) -> setprio(1) 16 MFMA
//     setprio(0) -> s_barrier.
//   - ONE s_waitcnt vmcnt(2) per K-tile (phase 0, after issuing next tile's
//     first half) — drains exactly the previous tile's 8 loads, keeps 2 in
//     flight. vmcnt(0) only on the last tile.
//   - Full 3-bit XOR chunk swizzle c^(r&7) (128B rows) on DMA source and
//     ds_read side; B-frags register-resident per K-tile.
// Epilogue (per-wave LDS bounce + coalesced short8 stores) unchanged.
// Attention (KV-resident), LN (wave-per-row), everything else unchanged.
// ============================================================================

#define B_  16
#define T_  32
#define L_  64
#define D_  768
#define H_  12
#define F_  2048
#define ZR_ 100
#define ZP_ 128
#define NP_ 512
#define EPS_ 1e-5f

// meta int offsets (d_ws as int*)
#define MI_NTOT  0
#define MI_NRESP 8
#define MI_OFF   32
#define MI_BIDX  64
#define MI_TIDX  576
#define MI_NODE  1088

// ws float offsets
#define WS_BIAS2 2048
#define WS_EMEAN 34816
#define WS_S     428032
#define WS_WST   428544    // bf16 weight stage, 1,769,472 ushorts (3.54 MB)
#define WS_BIG   1313280   // bf16 QKV/hidden region; fp32 Z overlay

// d_out float offsets (flat tuple: oh[512], ext_mask[32768], n_ext_adv[1],
// new_tree_lens[16], new_emb[25165824], new_msk[32768])
#define OUT_OH   0
#define OUT_EXT  512
#define OUT_NEA  33280
#define OUT_NTL  33281
#define OUT_NEMB 33297
#define OUT_NMSK 25199121
#define OUT_XSCR 33300   // bf16 X scratch (16B aligned), 32768*768 ushorts

typedef __attribute__((ext_vector_type(8))) short short8;
typedef __attribute__((ext_vector_type(4))) float f32x4;

__device__ inline float bf2f(unsigned s) {
  return __uint_as_float((s & 0xffffu) << 16);
}
__device__ inline unsigned short f2bf(float x) {
  unsigned u = __float_as_uint(x);
  u += 0x7fffu + ((u >> 16) & 1u);      // round-to-nearest-even
  return (unsigned short)(u >> 16);
}
__device__ inline unsigned pack2(float a, float b) {
  return (unsigned)f2bf(a) | ((unsigned)f2bf(b) << 16);
}

// ---------------------------------------------------------------------------
__global__ void meta_kernel(const int* __restrict__ tl, int* __restrict__ mi) {
  if (threadIdx.x != 0) return;
  int off = 0;
  for (int b = 0; b < B_; b++) {
    int nr = tl[b] - 1;
    mi[MI_NRESP + b] = nr;
    mi[MI_OFF + b] = off;
    off += nr;
  }
  mi[MI_NTOT] = off;
  for (int j = 0; j < NP_; j++) {
    int b = -1, t = 0;
    if (j < off) {
      b = 0;
      while (b + 1 < B_ && j >= mi[MI_OFF + b + 1]) b++;
      t = j - mi[MI_OFF + b] + 1;
    }
    mi[MI_BIDX + j] = b;
    mi[MI_TIDX + j] = t;
  }
}

// ---------------------------------------------------------------------------
// fp32 -> bf16 weight conversion (n multiple of 1024)
__global__ __launch_bounds__(256) void w2bf_kernel(const float* __restrict__ W,
                                                   unsigned short* __restrict__ o) {
  const int i = (blockIdx.x * 256 + threadIdx.x) * 4;
  float4 v = *(const float4*)(W + i);
  uint2 pk; pk.x = pack2(v.x, v.y); pk.y = pack2(v.z, v.w);
  *(uint2*)(o + i) = pk;
}

// ---------------------------------------------------------------------------
// X[j,l,:] bf16 = reply embedding (zero for padded j); bias2 = mask or -1e30
__global__ __launch_bounds__(192) void gather_kernel(
    const float* __restrict__ emb, const float* __restrict__ am,
    const int* __restrict__ mi, unsigned short* __restrict__ X,
    float* __restrict__ bias2) {
  const int blk = blockIdx.x;          // j*64 + l
  const int j = blk >> 6, l = blk & 63;
  const int ntot = mi[MI_NTOT];
  const int t = threadIdx.x;
  float4 v = make_float4(0.f, 0.f, 0.f, 0.f);
  if (j < ntot) {
    const int b = mi[MI_BIDX + j], tt = mi[MI_TIDX + j];
    v = ((const float4*)(emb + (size_t)((b * T_ + tt) * L_ + l) * D_))[t];
    if (t == 0) bias2[blk] = am[(b * T_ + tt) * L_ + l];
  } else {
    if (t == 0) bias2[blk] = -1e30f;
  }
  uint2 pk; pk.x = pack2(v.x, v.y); pk.y = pack2(v.z, v.w);
  *(uint2*)(X + (size_t)blk * D_ + t * 4) = pk;
}

// ---------------------------------------------------------------------------
__global__ __launch_bounds__(256) void emean_kernel(const unsigned short* __restrict__ X,
                                                    float* __restrict__ em) {
  const int j = blockIdx.x;
  int d = threadIdx.x;
  for (int c = 0; c < 3; c++, d += 256) {
    const unsigned short* p = X + (size_t)j * L_ * D_ + d;
    float s = 0.f;
    for (int l = 0; l < L_; l++) s += bf2f(p[l * D_]);
    em[j * D_ + d] = s * (1.f / 64.f);
  }
}

// ---------------------------------------------------------------------------
__device__ inline float blockSum256(float v, float* red) {
  #pragma unroll
  for (int o = 32; o > 0; o >>= 1) v += __shfl_down(v, o);
  const int lane = threadIdx.x & 63, wid = threadIdx.x >> 6;
  __syncthreads();
  if (lane == 0) red[wid] = v;
  __syncthreads();
  return red[0] + red[1] + red[2] + red[3];
}

// in-place LN, wave-per-row (4 rows/block, no barriers); skips padded rows
__global__ __launch_bounds__(256) void ln_kernel(unsigned short* __restrict__ X,
                                                 const float* __restrict__ g,
                                                 const float* __restrict__ bb,
                                                 const int* __restrict__ mi) {
  const int row = blockIdx.x * 4 + (threadIdx.x >> 6);
  if (row >= mi[MI_NTOT] * L_) return;
  const int lane = threadIdx.x & 63;
  unsigned short* p = X + (size_t)row * D_;
  float v[12];
  #pragma unroll
  for (int c = 0; c < 3; c++) {
    uint2 u = *(const uint2*)(p + lane * 4 + c * 256);
    v[c * 4 + 0] = bf2f(u.x); v[c * 4 + 1] = bf2f(u.x >> 16);
    v[c * 4 + 2] = bf2f(u.y); v[c * 4 + 3] = bf2f(u.y >> 16);
  }
  float s = 0.f;
  #pragma unroll
  for (int i = 0; i < 12; i++) s += v[i];
  #pragma unroll
  for (int o = 32; o > 0; o >>= 1) s += __shfl_xor(s, o);
  const float m = s * (1.f / 768.f);
  float q = 0.f;
  #pragma unroll
  for (int i = 0; i < 12; i++) { v[i] -= m; q += v[i] * v[i]; }
  #pragma unroll
  for (int o = 32; o > 0; o >>= 1) q += __shfl_xor(q, o);
  const float r = rsqrtf(q * (1.f / 768.f) + EPS_);
  #pragma unroll
  for (int c = 0; c < 3; c++) {
    const int d = lane * 4 + c * 256;
    float4 gv = *(const float4*)(g + d);
    float4 bv = *(const float4*)(bb + d);
    uint2 pk;
    pk.x = pack2(v[c * 4 + 0] * r * gv.x + bv.x, v[c * 4 + 1] * r * gv.y + bv.y);
    pk.y = pack2(v[c * 4 + 2] * r * gv.z + bv.z, v[c * 4 + 3] * r * gv.w + bv.w);
    *(uint2*)(p + d) = pk;
  }
}

// ---------------------------------------------------------------------------
// MFMA bf16 GEMM, 8-phase schedule: C[M,N] = [C +] act(A @ W^T + bias).
// 256x256 tile, 512 thr (8 waves 2x4, wave tile 128x64). K mult of 64,
// N mult of 256. BK=64, 2 K-tile LDS dbufs (128 KB): A[256][64] + B[256][64]
// bf16 per buffer, row = 128 B, chunk slot s of row r holds k-chunk s^(r&7).
// Per K-tile, 4 phases x {stage 1 half-tile || ds_read subtile -> barrier ->
// lgkmcnt(0)+sched_barrier -> setprio(1) 16 MFMA setprio(0) -> barrier};
// one vmcnt(2) per K-tile at phase 0 (counted; vmcnt(0) only on last tile).
// B-frags (8 ds_read) register-resident per K-tile; A-frags 4/phase.
// Epilogue: two 64x64 passes via per-wave 8KB LDS slice -> coalesced short8
// stores (+ residual add at readback for ADD).
template <int ACT, bool ADD>
__global__ __launch_bounds__(512) void gemm_mfma(
    const unsigned short* __restrict__ A, int lda, int K,
    const unsigned short* __restrict__ W, int ldw,
    const float* __restrict__ bias,
    unsigned short* __restrict__ C, int ldc,
    const int* __restrict__ mi) {
  const int rows = mi[MI_NTOT] * 64;
  const int row0 = blockIdx.x * 256;
  if (row0 >= rows) return;
  const int col0 = blockIdx.y * 256;
  __shared__ unsigned short Sh[2 * 32768];   // 2 dbuf x (A 32KB + B 32KB) = 128KB
  const int t = threadIdx.x;
  const int lane = t & 63, w = t >> 6;        // 8 waves
  const int wr = w >> 2, wc = w & 3;          // 2x4 wave grid, tile 128x64
  const int quad = lane >> 4, l15 = lane & 15;
  f32x4 acc[8][4];
  #pragma unroll
  for (int i = 0; i < 8; i++)
    #pragma unroll
    for (int j = 0; j < 4; j++) acc[i][j] = (f32x4){0.f, 0.f, 0.f, 0.f};

  // staging per-thread constants: thread covers rows j*64 + w*8 + (lane>>3),
  // slot s = lane&7 holds global k-chunk s ^ (lane>>3)  (row&7 == lane>>3)
  const int sr  = w * 8 + (lane >> 3);
  const int cc8 = ((lane & 7) ^ (lane >> 3)) * 8;

  // fragment ds_read offsets (ushort units); row*64 + slot*8, slot = c^(r&7)
  int aoffm[8], boffn[4];
  #pragma unroll
  for (int m = 0; m < 8; m++) aoffm[m] = (wr * 128 + m * 16 + l15) * 64;
  #pragma unroll
  for (int n = 0; n < 4; n++) boffn[n] = (wc * 64 + n * 16 + l15) * 64;
  const int e7 = l15 & 7;
  const int pq0 = ((quad)     ^ e7) * 8;     // kc=0 chunk slot
  const int pq1 = ((4 + quad) ^ e7) * 8;     // kc=1 chunk slot

  // stage half h (0/1) of matrix (0=A,1=B) for K-tile kt into buffer bi
#define STG(bi_, mat_, h_, kt_)                                                \
  { const unsigned short* gp_ = (mat_) ? W : A;                                \
    const int ld_ = (mat_) ? ldw : lda;                                        \
    const int b0_ = (mat_) ? col0 : row0;                                      \
    _Pragma("unroll")                                                          \
    for (int j_ = 0; j_ < 2; j_++) {                                           \
      const unsigned short* src_ =                                             \
          gp_ + (size_t)(b0_ + (h_) * 128 + j_ * 64 + sr) * ld_ +              \
          (kt_) * 64 + cc8;                                                    \
      __builtin_amdgcn_global_load_lds(                                        \
          (const __attribute__((address_space(1))) void*)src_,                 \
          (__attribute__((address_space(3))) void*)(Sh + (bi_) * 32768 +       \
              (mat_) * 16384 + (h_) * 8192 + j_ * 4096 + w * 512),             \
          16, 0, 0);                                                           \
    } }

  const int NT = K >> 6;     // 64-k tiles (all call sites: 12 or 32)
  // prologue: tile 0 into buf 0 (8 loads/thread)
  STG(0, 0, 0, 0); STG(0, 0, 1, 0); STG(0, 1, 0, 0); STG(0, 1, 1, 0);

  for (int kt = 0; kt < NT; kt++) {
    const int cur = kt & 1, nxt = cur ^ 1;
    const unsigned short* SA = Sh + cur * 32768;
    const unsigned short* SB = SA + 16384;
    const bool more = (kt + 1 < NT);
    short8 bfr[4][2];
    #pragma unroll
    for (int p = 0; p < 4; p++) {
      // ---- stage one half-tile of the next K-tile
      if (more) {
        if      (p == 0) STG(nxt, 0, 0, kt + 1)
        else if (p == 1) STG(nxt, 0, 1, kt + 1)
        else if (p == 2) STG(nxt, 1, 0, kt + 1)
        else             STG(nxt, 1, 1, kt + 1)
      }
      if (p == 0) {
        // counted wait: older 8 loads (this tile) retire; the 2 just-issued
        // stay in flight. Barrier makes cross-wave staging visible.
        if (more) asm volatile("s_waitcnt vmcnt(2)" ::: "memory");
        else      asm volatile("s_waitcnt vmcnt(0)" ::: "memory");
        __builtin_amdgcn_s_barrier();
      }
      // ---- ds_read subtile
      short8 afr[2][2];
      if (p == 0) {
        #pragma unroll
        for (int n = 0; n < 4; n++) {
          bfr[n][0] = *(const short8*)(SB + boffn[n] + pq0);
          bfr[n][1] = *(const short8*)(SB + boffn[n] + pq1);
        }
      }
      #pragma unroll
      for (int i = 0; i < 2; i++) {
        afr[i][0] = *(const short8*)(SA + aoffm[2 * p + i] + pq0);
        afr[i][1] = *(const short8*)(SA + aoffm[2 * p + i] + pq1);
      }
      if (p != 0) __builtin_amdgcn_s_barrier();
      asm volatile("s_waitcnt lgkmcnt(0)" ::: "memory");
      __builtin_amdgcn_sched_barrier(0);
      // ---- MFMA cluster (16)
      __builtin_amdgcn_s_setprio(1);
      #pragma unroll
      for (int i = 0; i < 2; i++)
        #pragma unroll
        for (int n = 0; n < 4; n++) {
          acc[2 * p + i][n] = __builtin_amdgcn_mfma_f32_16x16x32_bf16(
              afr[i][0], bfr[n][0], acc[2 * p + i][n], 0, 0, 0);
          acc[2 * p + i][n] = __builtin_amdgcn_mfma_f32_16x16x32_bf16(
              afr[i][1], bfr[n][1], acc[2 * p + i][n], 0, 0, 0);
        }
      __builtin_amdgcn_s_setprio(0);
      __builtin_amdgcn_s_barrier();
    }
  }
  __syncthreads();           // LDS now dead -> reuse as epilogue bounce
#undef STG

  // epilogue: C/D layout col = lane&15, row = quad*4 + reg. Two 64x64 passes
  // per wave through its private 8KB slice, then coalesced short8 stores
  // (8 per lane per pass). Residual add (ADD) at readback.
  unsigned short* slice = Sh + w * 4096;
  float bv[4];
  #pragma unroll
  for (int n = 0; n < 4; n++) bv[n] = bias[col0 + wc * 64 + n * 16 + l15];
  #pragma unroll
  for (int p = 0; p < 2; p++) {
    #pragma unroll
    for (int mm = 0; mm < 4; mm++) {
      #pragma unroll
      for (int reg = 0; reg < 4; reg++) {
        const int r64 = mm * 16 + quad * 4 + reg;
        #pragma unroll
        for (int n = 0; n < 4; n++) {
          float x = acc[p * 4 + mm][n][reg] + bv[n];
          if (ACT == 1) x = fmaxf(x, 0.f);
          slice[r64 * 64 + n * 16 + l15] = f2bf(x);
        }
      }
    }
    unsigned short* crow =
        C + (size_t)(row0 + wr * 128 + p * 64) * ldc + col0 + wc * 64;
    #pragma unroll
    for (int i = 0; i < 8; i++) {
      const int j = i * 64 + lane;           // 16B chunk 0..511 of 64x64 tile
      const int r64 = j >> 3, c8 = (j & 7) * 8;
      short8 v = *(const short8*)(slice + j * 8);
      unsigned short* cp = crow + (size_t)r64 * ldc + c8;
      if (ADD) {
        short8 cv = *(const short8*)cp;
        #pragma unroll
        for (int e = 0; e < 8; e++)
          v[e] = (short)f2bf(bf2f((unsigned short)v[e]) +
                             bf2f((unsigned short)cv[e]));
      }
      *(short8*)cp = v;
    }
  }
}

// ---------------------------------------------------------------------------
// VALU GEMM (kept for ragged pe/pd only): C = act(A @ W^T + b)
// AT: 0 fp32 A, 1 bf16 A.  CT: 0 fp32 C, 1 bf16 C.
template <int ACT, int AT, int CT>
__global__ __launch_bounds__(256) void gemm_kernel(
    const void* __restrict__ Av, int lda, int kloop,
    const float* __restrict__ W, int kw, int nreal,
    const float* __restrict__ bias,
    void* __restrict__ Cv, int ldc,
    const int* __restrict__ mi) {
  if ((int)blockIdx.x >= mi[MI_NTOT]) return;
  __shared__ float As[16][68];
  __shared__ float Ws[16][68];
  const int t = threadIdx.x;
  const int tx = t & 15, ty = t >> 4;
  const int lrow = t >> 2, lkg = (t & 3) * 4;
  const size_t row0 = (size_t)blockIdx.x * 64;
  const int col0 = blockIdx.y * 64;
  float acc[4][4] = {};
  for (int k0 = 0; k0 < kloop; k0 += 16) {
    float a4[4];
    if (AT == 0) {
      float4 av = *(const float4*)((const float*)Av + (row0 + lrow) * (size_t)lda + k0 + lkg);
      a4[0] = av.x; a4[1] = av.y; a4[2] = av.z; a4[3] = av.w;
    } else {
      uint2 u = *(const uint2*)((const unsigned short*)Av + (row0 + lrow) * (size_t)lda + k0 + lkg);
      a4[0] = bf2f(u.x); a4[1] = bf2f(u.x >> 16);
      a4[2] = bf2f(u.y); a4[3] = bf2f(u.y >> 16);
    }
    float wv[4];
    const int wn = col0 + lrow;
    #pragma unroll
    for (int i = 0; i < 4; i++) {
      const int k = k0 + lkg + i;
      wv[i] = (wn < nreal && k < kw) ? W[(size_t)wn * kw + k] : 0.f;
    }
    __syncthreads();
    As[lkg + 0][lrow] = a4[0]; As[lkg + 1][lrow] = a4[1];
    As[lkg + 2][lrow] = a4[2]; As[lkg + 3][lrow] = a4[3];
    Ws[lkg + 0][lrow] = wv[0]; Ws[lkg + 1][lrow] = wv[1];
    Ws[lkg + 2][lrow] = wv[2]; Ws[lkg + 3][lrow] = wv[3];
    __syncthreads();
    #pragma unroll
    for (int kk = 0; kk < 16; kk++) {
      float4 av4 = *(const float4*)(&As[kk][ty * 4]);
      float4 wv4 = *(const float4*)(&Ws[kk][tx * 4]);
      float aa[4] = {av4.x, av4.y, av4.z, av4.w};
      float ww[4] = {wv4.x, wv4.y, wv4.z, wv4.w};
      #pragma unroll
      for (int i = 0; i < 4; i++)
        #pragma unroll
        for (int j = 0; j < 4; j++) acc[i][j] += aa[i] * ww[j];
    }
  }
  const int n0 = col0 + tx * 4;
  float bv[4];
  #pragma unroll
  for (int j = 0; j < 4; j++) bv[j] = (n0 + j < nreal) ? bias[n0 + j] : 0.f;
  #pragma unroll
  for (int i = 0; i < 4; i++) {
    float v[4];
    #pragma unroll
    for (int j = 0; j < 4; j++) {
      float x = acc[i][j] + bv[j];
      if (ACT == 1) x = fmaxf(x, 0.f);
      if (ACT == 2) x = tanhf(x);
      v[j] = x;
    }
    if (CT == 0) {
      float* cp = (float*)Cv + (row0 + ty * 4 + i) * (size_t)ldc + n0;
      *(float4*)cp = make_float4(v[0], v[1], v[2], v[3]);
    } else {
      unsigned short* cp = (unsigned short*)Cv + (row0 + ty * 4 + i) * (size_t)ldc + n0;
      uint2 pk; pk.x = pack2(v[0], v[1]); pk.y = pack2(v[2], v[3]);
      *(uint2*)cp = pk;
    }
  }
}

// ---------------------------------------------------------------------------
// MFMA attention, KV-resident: one block per (l, h), 8 waves (512 thr).
// Stage ALL K (global_load_lds, pre-swizzled source -> linear LDS) and V^T
// (manual transpose scatter) once; single barrier; then each wave free-runs
// q-tiles (16 rows/wave, 128/block) x kv-tiles with zero global loads and
// zero barriers (P staging per-wave). O bf16 overwrites Q columns of QKV
// (disjoint from staged K/V columns; each wave owns its rows -> race-free).
// LDS tile swizzle: elem(row,col) at row*64 + ((col>>3)^(row&7))*8 + (col&7).
__global__ __launch_bounds__(512) void attn_kernel(
    unsigned short* __restrict__ QKV, const float* __restrict__ bias2,
    const int* __restrict__ mi) {
  const int ntot = mi[MI_NTOT];
  const int l = blockIdx.x, h = blockIdx.y;
  const int ntk = (ntot + 63) >> 6;     // kv tiles (padded keys masked by bias)
  __shared__ unsigned short Ks[512 * 64];   // K rows [m][d], swizzled
  __shared__ unsigned short Vt[8 * 4096];   // per-tile V^T [d][m], swizzled
  __shared__ unsigned short Ps[8][1024];    // per-wave P / O-bounce
  __shared__ float bs[512];                 // bias column for this l
  const int t = threadIdx.x;
  const int lane = t & 63, w = t >> 6;
  const int quad = lane >> 4, l15 = lane & 15;

  // ---- stage K: linear LDS dst, source chunk pre-swizzled so slot g of row
  // m holds chunk g ^ (m&7) (matches the ds_read swizzle below)
  {
    const int sub = lane >> 3;              // low 3 bits of m
    const int cc = (lane & 7) ^ sub;        // source chunk for this slot
    for (int it = 0; it < ntk; it++) {
      const int m = it * 64 + w * 8 + sub;
      const unsigned short* src =
          QKV + (size_t)(m * L_ + l) * 2304 + 768 + h * 64 + cc * 8;
      __builtin_amdgcn_global_load_lds(
          (const __attribute__((address_space(1))) void*)src,
          (__attribute__((address_space(3))) void*)(Ks + it * 4096 + w * 512),
          16, 0, 0);
    }
  }
  // ---- stage V transposed: thread t -> m = t&63, d in [(t>>6)*8, +8)
  {
    const int m = t & 63;
    const int d0 = (t >> 6) * 8;
    for (int mt = 0; mt < ntk; mt++) {
      short8 v = *(const short8*)(
          QKV + (size_t)((mt * 64 + m) * L_ + l) * 2304 + 1536 + h * 64 + d0);
      #pragma unroll
      for (int i = 0; i < 8; i++) {
        const int d = d0 + i;
        Vt[mt * 4096 + d * 64 + (((m >> 3) ^ (d & 7)) * 8) + (m & 7)] =
            (unsigned short)v[i];
      }
    }
  }
  // ---- stage bias column (padded m already -1e30 from gather)
  bs[t] = bias2[t * 64 + l];
  __syncthreads();

  const int nqt = (ntot + 127) >> 7;
  for (int qt = 0; qt < nqt; qt++) {
    const int qbase = qt * 128 + w * 16;
    if (qbase >= ntot) continue;

    // Q A-frags direct from global (2 x 16B per lane)
    short8 af[2];
    #pragma unroll
    for (int kc = 0; kc < 2; kc++)
      af[kc] = *(const short8*)(
          QKV + (size_t)((qbase + l15) * L_ + l) * 2304 + h * 64 + (kc * 4 + quad) * 8);

    f32x4 oa[4];
    float runmax[4], runsum[4];
    #pragma unroll
    for (int f = 0; f < 4; f++) oa[f] = (f32x4){0.f, 0.f, 0.f, 0.f};
    #pragma unroll
    for (int r2 = 0; r2 < 4; r2++) { runmax[r2] = -3.0e38f; runsum[r2] = 0.f; }

    for (int mt = 0; mt < ntk; mt++) {
      // ---- S = Q @ K^T  (C layout: row q = quad*4+reg, col m = cb*16+l15)
      f32x4 sv[4];
      #pragma unroll
      for (int cb = 0; cb < 4; cb++) {
        sv[cb] = (f32x4){0.f, 0.f, 0.f, 0.f};
        const int mrow = mt * 64 + cb * 16 + l15;
        #pragma unroll
        for (int kc = 0; kc < 2; kc++) {
          short8 bk = *(const short8*)(
              Ks + mrow * 64 + (((kc * 4 + quad) ^ (mrow & 7)) * 8));
          sv[cb] = __builtin_amdgcn_mfma_f32_16x16x32_bf16(af[kc], bk, sv[cb], 0, 0, 0);
        }
      }

      // ---- online softmax (state per q-row = quad*4+reg)
      float bj[4];
      #pragma unroll
      for (int cb = 0; cb < 4; cb++) bj[cb] = bs[mt * 64 + cb * 16 + l15];
      float pj[4][4];   // [cb][reg]
      #pragma unroll
      for (int cb = 0; cb < 4; cb++)
        #pragma unroll
        for (int r2 = 0; r2 < 4; r2++) pj[cb][r2] = sv[cb][r2] * 0.125f + bj[cb];
      float tmax[4];
      #pragma unroll
      for (int r2 = 0; r2 < 4; r2++)
        tmax[r2] = fmaxf(fmaxf(pj[0][r2], pj[1][r2]), fmaxf(pj[2][r2], pj[3][r2]));
      #pragma unroll
      for (int o2 = 1; o2 < 16; o2 <<= 1)
        #pragma unroll
        for (int r2 = 0; r2 < 4; r2++) tmax[r2] = fmaxf(tmax[r2], __shfl_xor(tmax[r2], o2));
      float tsum[4];
      #pragma unroll
      for (int r2 = 0; r2 < 4; r2++) {
        const float nmax = fmaxf(runmax[r2], tmax[r2]);
        const float alpha = __expf(runmax[r2] - nmax);
        runmax[r2] = nmax;
        float s0 = 0.f;
        #pragma unroll
        for (int cb = 0; cb < 4; cb++) { pj[cb][r2] = __expf(pj[cb][r2] - nmax); s0 += pj[cb][r2]; }
        tsum[r2] = s0;
        runsum[r2] *= alpha;
        #pragma unroll
        for (int f = 0; f < 4; f++) oa[f][r2] *= alpha;
      }
      #pragma unroll
      for (int o2 = 1; o2 < 16; o2 <<= 1)
        #pragma unroll
        for (int r2 = 0; r2 < 4; r2++) tsum[r2] += __shfl_xor(tsum[r2], o2);
      #pragma unroll
      for (int r2 = 0; r2 < 4; r2++) runsum[r2] += tsum[r2];

      // ---- P -> per-wave LDS (A-operand layout, bf16)
      #pragma unroll
      for (int cb = 0; cb < 4; cb++) {
        const int m = cb * 16 + l15;
        #pragma unroll
        for (int r2 = 0; r2 < 4; r2++) {
          const int q = quad * 4 + r2;
          Ps[w][q * 64 + (((m >> 3) ^ (q & 7)) * 8) + (m & 7)] = f2bf(pj[cb][r2]);
        }
      }
      // ---- O += P @ V
      short8 pa[2];
      #pragma unroll
      for (int kc = 0; kc < 2; kc++)
        pa[kc] = *(const short8*)(
            &Ps[w][l15 * 64 + (((kc * 4 + quad) ^ (l15 & 7)) * 8)]);
      #pragma unroll
      for (int f = 0; f < 4; f++) {
        const int d = f * 16 + l15;
        #pragma unroll
        for (int kc = 0; kc < 2; kc++) {
          short8 bv = *(const short8*)(
              Vt + mt * 4096 + d * 64 + (((kc * 4 + quad) ^ (d & 7)) * 8));
          oa[f] = __builtin_amdgcn_mfma_f32_16x16x32_bf16(pa[kc], bv, oa[f], 0, 0, 0);
        }
      }
    }

    // ---- epilogue: normalize, bounce through per-wave Ps, 16B stores
    #pragma unroll
    for (int r2 = 0; r2 < 4; r2++) {
      const float inv = 1.f / runsum[r2];
      const int q = quad * 4 + r2;
      #pragma unroll
      for (int f = 0; f < 4; f++)
        Ps[w][q * 64 + f * 16 + l15] = f2bf(oa[f][r2] * inv);
    }
    #pragma unroll
    for (int i = 0; i < 2; i++) {
      const int j = lane + i * 64;          // 16B chunk index 0..127
      const int q = j >> 3, c8 = j & 7;
      short8 v = *(const short8*)(&Ps[w][j * 8]);
      *(short8*)(QKV + (size_t)((qbase + q) * L_ + l) * 2304 + h * 64 + c8 * 8) = v;
    }
  }
}

// ---------------------------------------------------------------------------
__global__ __launch_bounds__(256) void score_kernel(const unsigned short* __restrict__ X,
                                                    const float* __restrict__ em,
                                                    float* __restrict__ Sv) {
  const int j = blockIdx.x;
  const int t = threadIdx.x;
  __shared__ float red[4];
  float part = 0.f;
  for (int c = 0; c < 3; c++) {
    const int d = t + c * 256;
    const unsigned short* p = X + (size_t)j * L_ * D_ + d;
    float s = 0.f;
    for (int l = 0; l < L_; l++) s += bf2f(p[l * D_]);
    const float diff = s * (1.f / 64.f) - em[j * D_ + d];
    part += diff * diff;
  }
  const float tot = blockSum256(part, red);
  if (t == 0) Sv[j] = tot;
}

// ---------------------------------------------------------------------------
__global__ __launch_bounds__(256) void finalize_kernel(const float* __restrict__ Sv,
                                                       int* __restrict__ mi,
                                                       float* __restrict__ out) {
  const int t = threadIdx.x;
  if (t < B_) {
    const int nr = mi[MI_NRESP + t];
    float best = 3.0e38f; int bi = 0;
    for (int j = 0; j < nr; j++) {
      const float v = Sv[j];
      if (v < best) { best = v; bi = j; }
    }
    mi[MI_NODE + t] = bi + 1;
    int next = nr / 20; if (next < 1) next = 1;
    out[OUT_NTL + t] = (float)(1 + next);
  }
  if (t == 0) out[OUT_NEA] = 0.f;
  __syncthreads();
  for (int idx = t; idx < B_ * T_; idx += 256) {
    const int b = idx >> 5, tt = idx & 31;
    out[OUT_OH + idx] = (tt == 0 || tt == mi[MI_NODE + b]) ? 1.f : 0.f;
  }
}

// ---------------------------------------------------------------------------
__global__ __launch_bounds__(256) void maskout_kernel(const float* __restrict__ am,
                                                      const int* __restrict__ mi,
                                                      float* __restrict__ out) {
  const int idx = blockIdx.x * 256 + threadIdx.x;
  const int b = idx >> 11, rem = idx & 2047;
  const int tt = rem >> 6, l = rem & 63;
  const int node = mi[MI_NODE + b];
  out[OUT_EXT + idx] = (tt == 0 || tt == node) ? 1.f : 0.f;
  float nm;
  if (tt == 0)      nm = am[(b * T_) * L_ + l];
  else if (tt == 1) nm = am[(b * T_ + node) * L_ + l];
  else              nm = 0.f;
  out[OUT_NMSK + idx] = nm;
}

// ---------------------------------------------------------------------------
__global__ __launch_bounds__(192) void newemb_kernel(const float* __restrict__ emb,
                                                     const int* __restrict__ mi,
                                                     float* __restrict__ out) {
  const int blk = blockIdx.x;
  const int b = blk >> 11, rem = blk & 2047;
  const int tt = rem >> 6, l = rem & 63;
  const int srct = (tt == 1) ? mi[MI_NODE + b] : 0;
  const float4 v = ((const float4*)(emb + (size_t)((b * T_ + srct) * L_ + l) * D_))[threadIdx.x];
  float* dst = out + OUT_NEMB + (size_t)blk * D_ + threadIdx.x * 4;
  dst[0] = v.x; dst[1] = v.y; dst[2] = v.z; dst[3] = v.w;
}

// ===========================================================================
extern "C" void kernel_launch(void* const* d_in, const int* in_sizes, int n_in,
                              void* d_out, int out_size, void* d_ws, size_t ws_size,
                              hipStream_t stream) {
  (void)in_sizes; (void)n_in; (void)out_size; (void)ws_size;
  const int*   tl  = (const int*)d_in[0];
  const float* emb = (const float*)d_in[1];
  const float* am  = (const float*)d_in[2];
  const float* P[28];
  for (int i = 0; i < 28; i++) P[i] = (const float*)d_in[3 + i];

  float* wsf   = (float*)d_ws;
  int*   mi    = (int*)d_ws;
  float* bias2 = wsf + WS_BIAS2;
  float* emean = wsf + WS_EMEAN;
  float* Sv    = wsf + WS_S;
  unsigned short* Wst = (unsigned short*)(wsf + WS_WST);
  unsigned short* BIG = (unsigned short*)(wsf + WS_BIG);
  float* Zb    = wsf + WS_BIG;                      // fp32 Z overlay (enc->dec)
  float* out   = (float*)d_out;
  unsigned short* X = (unsigned short*)(out + OUT_XSCR);  // bf16 residual

  meta_kernel<<<1, 64, 0, stream>>>(tl, mi);
  gather_kernel<<<NP_ * L_, 192, 0, stream>>>(emb, am, mi, X, bias2);
  emean_kernel<<<NP_, 256, 0, stream>>>(X, emean);

  const int RTM = NP_ * 64 / 256;  // 128 row tiles (256 rows each)
  const int LNB = NP_ * L_ / 4;    // 8192 ln blocks (4 rows each)
  for (int s = 0; s < 2; s++) {
    const float* const* q = P + s * 12;
    for (int i = 0; i < 2; i++) {
      // QKV: X -> BIG [rows, 2304]
      w2bf_kernel<<<(3 * D_ * D_) / 1024, 256, 0, stream>>>(q[0] + (size_t)i * 3 * D_ * D_, Wst);
      gemm_mfma<0, false><<<dim3(RTM, 9), 512, 0, stream>>>(
          X, D_, D_, Wst, D_, q[1] + i * 3 * D_, BIG, 3 * D_, mi);
      attn_kernel<<<dim3(L_, H_), 512, 0, stream>>>(BIG, bias2, mi);
      // out-proj: O (Q cols of BIG, lda=2304) -> += X
      w2bf_kernel<<<(D_ * D_) / 1024, 256, 0, stream>>>(q[2] + (size_t)i * D_ * D_, Wst);
      gemm_mfma<0, true><<<dim3(RTM, 3), 512, 0, stream>>>(
          BIG, 3 * D_, D_, Wst, D_, q[3] + i * D_, X, D_, mi);
      ln_kernel<<<LNB, 256, 0, stream>>>(X, q[4] + i * D_, q[5] + i * D_, mi);
      // FFN1: X -> hidden BIG [rows, 2048] (relu)
      w2bf_kernel<<<(F_ * D_) / 1024, 256, 0, stream>>>(q[6] + (size_t)i * F_ * D_, Wst);
      gemm_mfma<1, false><<<dim3(RTM, 8), 512, 0, stream>>>(
          X, D_, D_, Wst, D_, q[7] + i * F_, BIG, F_, mi);
      // FFN2: hidden -> += X
      w2bf_kernel<<<(D_ * F_) / 1024, 256, 0, stream>>>(q[8] + (size_t)i * D_ * F_, Wst);
      gemm_mfma<0, true><<<dim3(RTM, 3), 512, 0, stream>>>(
          BIG, F_, F_, Wst, F_, q[9] + i * D_, X, D_, mi);
      ln_kernel<<<LNB, 256, 0, stream>>>(X, q[10] + i * D_, q[11] + i * D_, mi);
    }
    if (s == 0) {
      // z = tanh(h @ pe_w^T + pe_b) -> Z fp32 (stride 128, cols 100..127 = 0)
      gemm_kernel<2, 1, 0><<<dim3(NP_, 2), 256, 0, stream>>>(
          X, D_, D_, P[24], D_, ZR_, P[25], Zb, ZP_, mi);
      // zd = tanh(z @ pd_w^T + pd_b) -> X bf16 (decoder input)
      gemm_kernel<2, 0, 1><<<dim3(NP_, 12), 256, 0, stream>>>(
          Zb, ZP_, ZP_, P[26], ZR_, D_, P[27], X, D_, mi);
    }
  }

  score_kernel<<<NP_, 256, 0, stream>>>(X, emean, Sv);
  finalize_kernel<<<1, 256, 0, stream>>>(Sv, mi, out);
  maskout_kernel<<<128, 256, 0, stream>>>(am, mi, out);
  newemb_kernel<<<B_ * T_ * L_, 192, 0, stream>>>(emb, mi, out);
}